// Round 11
// baseline (1245.401 us; speedup 1.0000x reference)
//
#include <hip/hip_runtime.h>
#include <hip/hip_bf16.h>
#include <math.h>

// DeepseekV32 MLA attention + lightning indexer, MI355X (gfx950).
// Round 13: k_scores_mfma (173 us; 6300 cyc per h-iter vs ~250 compute —
// Q re-staged from global inside the barrier pair every head) -> k_scores2:
// (1) register-prefetch Q for head h+1 during head h's compute (issue-early /
// ds_write-late), (2) drop Wsh from LDS (direct L2 reads, prefetched) so LDS
// falls 56.8 -> 51 KB = 3 blocks/CU (+50% occupancy). Same math order.

namespace {

constexpr int T_    = 2048;
constexpr int HID_  = 7168;
constexpr int H_    = 16;
constexpr int QLR_  = 1536;
constexpr int KVLR_ = 512;
constexpr int IH_   = 32;
constexpr int ID_   = 128;
constexpr int TOPK_ = 512;
constexpr float EPS_    = 1e-6f;
constexpr float SCALE_  = 0.07216878364870322f;   // (128+64)^-0.5
constexpr float ISCALE_ = 0.08838834764831845f;   // 128^-0.5
constexpr float WSCALE_ = 0.17677669529663687f;   // 32^-0.5

// hidden GEMM: split-K config
constexpr int KSPLIT_ = 8;
constexpr int KC_     = HID_ / KSPLIT_;  // 896 = 28 steps of 32
constexpr int NC_     = 160;             // 128 (Wik) + 32 (Ww)

typedef __attribute__((ext_vector_type(8))) short bf16x8;
typedef __attribute__((ext_vector_type(4))) float f32x4;

__device__ __forceinline__ unsigned int mono(float x) {
  unsigned int u = __float_as_uint(x);
  return (u & 0x80000000u) ? ~u : (u | 0x80000000u);
}

__device__ __forceinline__ unsigned short f2bf(float x) {
  unsigned int u = __float_as_uint(x);
  u += 0x7FFFu + ((u >> 16) & 1u);
  return (unsigned short)(u >> 16);
}

__device__ __forceinline__ float bf2f(unsigned short h) {
  return __uint_as_float((unsigned int)h << 16);
}

// ---------------- rope tables ----------------
__global__ void k_tables(const int* __restrict__ pos, float* __restrict__ cosT,
                         float* __restrict__ sinT) {
  int idx = blockIdx.x * 256 + threadIdx.x;
  if (idx >= T_ * 32) return;
  int t = idx >> 5, i = idx & 31;
  float invf = (float)pow(10000.0, -(double)i / 32.0);
  float ang = (float)pos[t] * invf;
  cosT[idx] = cosf(ang);
  sinT[idx] = sinf(ang);
}

// ---------------- rmsnorm: bf16 hi (+ optional lo residual) ----------------
template <int N>
__launch_bounds__(256)
__global__ void k_rms(const float* __restrict__ x, const float* __restrict__ w,
                      unsigned short* __restrict__ yhi, unsigned short* __restrict__ ylo) {
  int t = blockIdx.x;
  const float* xr = x + (size_t)t * N;
  float ss = 0.f;
  for (int c = threadIdx.x; c < N; c += 256) { float v = xr[c]; ss += v * v; }
  __shared__ float red[256];
  red[threadIdx.x] = ss;
  __syncthreads();
  for (int off = 128; off > 0; off >>= 1) {
    if (threadIdx.x < off) red[threadIdx.x] += red[threadIdx.x + off];
    __syncthreads();
  }
  float sc = rsqrtf(red[0] * (1.f / N) + EPS_);
  unsigned short* yhr = yhi + (size_t)t * N;
  unsigned short* ylr = ylo ? ylo + (size_t)t * N : nullptr;
  for (int c = threadIdx.x; c < N; c += 256) {
    float v = xr[c] * sc * w[c];
    unsigned short hb = f2bf(v);
    yhr[c] = hb;
    if (ylr) ylr[c] = f2bf(v - bf2f(hb));
  }
}

// ---------------- transpose-cast: W (K x N, f32) -> Wt (N x K, bf16) ----------------
__launch_bounds__(256)
__global__ void k_tc(const float* __restrict__ W, unsigned short* __restrict__ Wt,
                     int K, int N) {
  __shared__ float tile[64][65];
  int k0 = blockIdx.y * 64, n0 = blockIdx.x * 64;
  int tid = threadIdx.x;
#pragma unroll
  for (int i = 0; i < 16; ++i) {
    int e = i * 256 + tid;
    int r = e >> 6, c = e & 63;
    tile[r][c] = W[(size_t)(k0 + r) * N + n0 + c];
  }
  __syncthreads();
#pragma unroll
  for (int i = 0; i < 16; ++i) {
    int e = i * 256 + tid;
    int r = e >> 6, c = e & 63;
    Wt[(size_t)(n0 + r) * K + k0 + c] = f2bf(tile[c][r]);
  }
}

// ---------------- transpose + split-cast: W (K x N, f32) -> Wt_hi/Wt_lo (N x K) ----------------
__launch_bounds__(256)
__global__ void k_tc2(const float* __restrict__ W, unsigned short* __restrict__ Wth,
                      unsigned short* __restrict__ Wtl, int K, int N) {
  __shared__ float tile[64][65];
  int k0 = blockIdx.y * 64, n0 = blockIdx.x * 64;
  int tid = threadIdx.x;
#pragma unroll
  for (int i = 0; i < 16; ++i) {
    int e = i * 256 + tid;
    int r = e >> 6, c = e & 63;
    tile[r][c] = W[(size_t)(k0 + r) * N + n0 + c];
  }
  __syncthreads();
#pragma unroll
  for (int i = 0; i < 16; ++i) {
    int e = i * 256 + tid;
    int r = e >> 6, c = e & 63;
    float v = tile[c][r];
    unsigned short hb = f2bf(v);
    size_t o = (size_t)(n0 + r) * K + k0 + c;
    Wth[o] = hb;
    Wtl[o] = f2bf(v - bf2f(hb));
  }
}

// ---------------- combined [Wik | Ww] transpose + split-cast -> (160 x 7168) hi/lo ----------------
__launch_bounds__(256)
__global__ void k_tc2w(const float* __restrict__ Wik, const float* __restrict__ Ww,
                       unsigned short* __restrict__ Bth, unsigned short* __restrict__ Btl) {
  __shared__ float tile[64][65];
  int k0 = blockIdx.x * 64;
  int ny = blockIdx.y;              // 0,1: Wik cols; 2: Ww cols (32)
  int ncols = (ny == 2) ? 32 : 64;
  int tid = threadIdx.x;
#pragma unroll
  for (int i = 0; i < 16; ++i) {
    int e = i * 256 + tid;
    int r = e >> 6, c = e & 63;
    if (c < ncols)
      tile[r][c] = (ny == 2) ? Ww[(size_t)(k0 + r) * 32 + c]
                             : Wik[(size_t)(k0 + r) * 128 + ny * 64 + c];
  }
  __syncthreads();
#pragma unroll
  for (int i = 0; i < 16; ++i) {
    int e = i * 256 + tid;
    int r = e >> 6, c = e & 63;
    if (r < ncols) {
      float v = tile[c][r];
      unsigned short hb = f2bf(v);
      size_t o = (size_t)(ny * 64 + r) * HID_ + k0 + c;
      Bth[o] = hb;
      Btl[o] = f2bf(v - bf2f(hb));
    }
  }
}

// ---------------- bf16 MFMA GEMM: C(M,N) f32 = A(M,K) bf16 @ Bt(N,K) bf16 ----------------
__launch_bounds__(256)
__global__ void k_gemm_bf(const unsigned short* __restrict__ A,
                          const unsigned short* __restrict__ Bt,
                          float* __restrict__ C, int M, int N, int K) {
  __shared__ unsigned short As[128][40];
  __shared__ unsigned short Bs[128][40];
  int m0 = blockIdx.y * 128, n0 = blockIdx.x * 128;
  int tid = threadIdx.x;
  int w = tid >> 6, lane = tid & 63;
  int quad = lane >> 4, l16 = lane & 15;
  int wr = w & 1, wc = w >> 1;
  f32x4 acc[4][4] = {};
  for (int k0 = 0; k0 < K; k0 += 32) {
    __syncthreads();
#pragma unroll
    for (int i = 0; i < 2; ++i) {
      int c = i * 256 + tid;
      int row = c >> 2, off = (c & 3) * 8;
      *(uint4*)&As[row][off] = *(const uint4*)&A[(size_t)(m0 + row) * K + k0 + off];
      *(uint4*)&Bs[row][off] = *(const uint4*)&Bt[(size_t)(n0 + row) * K + k0 + off];
    }
    __syncthreads();
    bf16x8 a[4], b[4];
#pragma unroll
    for (int mi = 0; mi < 4; ++mi) a[mi] = *(const bf16x8*)&As[64 * wr + 16 * mi + l16][quad * 8];
#pragma unroll
    for (int ni = 0; ni < 4; ++ni) b[ni] = *(const bf16x8*)&Bs[64 * wc + 16 * ni + l16][quad * 8];
#pragma unroll
    for (int mi = 0; mi < 4; ++mi)
#pragma unroll
      for (int ni = 0; ni < 4; ++ni)
        acc[mi][ni] = __builtin_amdgcn_mfma_f32_16x16x32_bf16(a[mi], b[ni], acc[mi][ni], 0, 0, 0);
  }
#pragma unroll
  for (int mi = 0; mi < 4; ++mi)
#pragma unroll
    for (int ni = 0; ni < 4; ++ni)
#pragma unroll
      for (int r = 0; r < 4; ++r) {
        int row = m0 + 64 * wr + 16 * mi + quad * 4 + r;
        int col = n0 + 64 * wc + 16 * ni + l16;
        C[(size_t)row * N + col] = acc[mi][ni][r];
      }
}

// ---------------- split-bf16 3-pass GEMM: C f32 = (Ah+Al)(M,K) @ (Bh+Bl)t(N,K) ----------------
__launch_bounds__(256)
__global__ void k_gemm3(const unsigned short* __restrict__ Ah,
                        const unsigned short* __restrict__ Al,
                        const unsigned short* __restrict__ Bth,
                        const unsigned short* __restrict__ Btl,
                        float* __restrict__ C, int M, int N, int K) {
  __shared__ unsigned short Ash[128][40];
  __shared__ unsigned short Asl[128][40];
  __shared__ unsigned short Bsh[128][40];
  __shared__ unsigned short Bsl[128][40];
  int m0 = blockIdx.y * 128, n0 = blockIdx.x * 128;
  int tid = threadIdx.x;
  int w = tid >> 6, lane = tid & 63;
  int quad = lane >> 4, l16 = lane & 15;
  int wr = w & 1, wc = w >> 1;
  f32x4 acc[4][4] = {};
  for (int k0 = 0; k0 < K; k0 += 32) {
    __syncthreads();
#pragma unroll
    for (int i = 0; i < 2; ++i) {
      int c = i * 256 + tid;
      int row = c >> 2, off = (c & 3) * 8;
      *(uint4*)&Ash[row][off] = *(const uint4*)&Ah[(size_t)(m0 + row) * K + k0 + off];
      *(uint4*)&Asl[row][off] = *(const uint4*)&Al[(size_t)(m0 + row) * K + k0 + off];
      *(uint4*)&Bsh[row][off] = *(const uint4*)&Bth[(size_t)(n0 + row) * K + k0 + off];
      *(uint4*)&Bsl[row][off] = *(const uint4*)&Btl[(size_t)(n0 + row) * K + k0 + off];
    }
    __syncthreads();
    bf16x8 ah[4], al[4];
#pragma unroll
    for (int mi = 0; mi < 4; ++mi) {
      ah[mi] = *(const bf16x8*)&Ash[64 * wr + 16 * mi + l16][quad * 8];
      al[mi] = *(const bf16x8*)&Asl[64 * wr + 16 * mi + l16][quad * 8];
    }
#pragma unroll
    for (int nh = 0; nh < 2; ++nh) {
      bf16x8 bh[2], bl[2];
#pragma unroll
      for (int nj = 0; nj < 2; ++nj) {
        int nrow = 64 * wc + 16 * (2 * nh + nj) + l16;
        bh[nj] = *(const bf16x8*)&Bsh[nrow][quad * 8];
        bl[nj] = *(const bf16x8*)&Bsl[nrow][quad * 8];
      }
#pragma unroll
      for (int mi = 0; mi < 4; ++mi)
#pragma unroll
        for (int nj = 0; nj < 2; ++nj) {
          int ni = 2 * nh + nj;
          acc[mi][ni] = __builtin_amdgcn_mfma_f32_16x16x32_bf16(ah[mi], bh[nj], acc[mi][ni], 0, 0, 0);
          acc[mi][ni] = __builtin_amdgcn_mfma_f32_16x16x32_bf16(ah[mi], bl[nj], acc[mi][ni], 0, 0, 0);
          acc[mi][ni] = __builtin_amdgcn_mfma_f32_16x16x32_bf16(al[mi], bh[nj], acc[mi][ni], 0, 0, 0);
        }
    }
  }
#pragma unroll
  for (int mi = 0; mi < 4; ++mi)
#pragma unroll
    for (int ni = 0; ni < 4; ++ni)
#pragma unroll
      for (int r = 0; r < 4; ++r) {
        int row = m0 + 64 * wr + 16 * mi + quad * 4 + r;
        int col = n0 + 64 * wc + 16 * ni + l16;
        C[(size_t)row * N + col] = acc[mi][ni][r];
      }
}

// ---------------- fused hidden GEMM: part[s] = hidden(64-tile, Kc) @ [Wik|Ww]^T ----------------
__launch_bounds__(256)
__global__ void k_hgemm(const float* __restrict__ hidden,
                        const unsigned short* __restrict__ Bth,
                        const unsigned short* __restrict__ Btl,
                        float* __restrict__ part) {
  __shared__ unsigned short Ash[64][40];
  __shared__ unsigned short Asl[64][40];
  __shared__ unsigned short Bsh[NC_][40];
  __shared__ unsigned short Bsl[NC_][40];
  int ks = blockIdx.x, m0 = blockIdx.y * 64;
  int kc0 = ks * KC_;
  int tid = threadIdx.x;
  int w = tid >> 6, lane = tid & 63;
  int quad = lane >> 4, l16 = lane & 15;
  int wr = w & 1, wc = w >> 1;   // wave: 32 rows x 80 cols
  f32x4 acc[2][5] = {};
  for (int s = 0; s < KC_ / 32; ++s) {
    int k0 = kc0 + s * 32;
    __syncthreads();
#pragma unroll
    for (int i = 0; i < 2; ++i) {
      int c = i * 256 + tid;          // 0..511
      int row = c >> 3, off = (c & 7) * 4;
      float4 v = *(const float4*)&hidden[(size_t)(m0 + row) * HID_ + k0 + off];
      ushort4 hv, lv;
      hv.x = f2bf(v.x); lv.x = f2bf(v.x - bf2f(hv.x));
      hv.y = f2bf(v.y); lv.y = f2bf(v.y - bf2f(hv.y));
      hv.z = f2bf(v.z); lv.z = f2bf(v.z - bf2f(hv.z));
      hv.w = f2bf(v.w); lv.w = f2bf(v.w - bf2f(hv.w));
      *(ushort4*)&Ash[row][off] = hv;
      *(ushort4*)&Asl[row][off] = lv;
    }
#pragma unroll
    for (int i = 0; i < 3; ++i) {
      int c = i * 256 + tid;          // 0..639 valid
      if (c < NC_ * 4) {
        int row = c >> 2, off = (c & 3) * 8;
        *(uint4*)&Bsh[row][off] = *(const uint4*)&Bth[(size_t)row * HID_ + k0 + off];
        *(uint4*)&Bsl[row][off] = *(const uint4*)&Btl[(size_t)row * HID_ + k0 + off];
      }
    }
    __syncthreads();
    bf16x8 ah[2], al[2];
#pragma unroll
    for (int mi = 0; mi < 2; ++mi) {
      ah[mi] = *(const bf16x8*)&Ash[32 * wr + 16 * mi + l16][quad * 8];
      al[mi] = *(const bf16x8*)&Asl[32 * wr + 16 * mi + l16][quad * 8];
    }
#pragma unroll
    for (int ni = 0; ni < 5; ++ni) {
      int nrow = 80 * wc + 16 * ni + l16;
      bf16x8 bh = *(const bf16x8*)&Bsh[nrow][quad * 8];
      bf16x8 bl = *(const bf16x8*)&Bsl[nrow][quad * 8];
#pragma unroll
      for (int mi = 0; mi < 2; ++mi) {
        acc[mi][ni] = __builtin_amdgcn_mfma_f32_16x16x32_bf16(ah[mi], bh, acc[mi][ni], 0, 0, 0);
        acc[mi][ni] = __builtin_amdgcn_mfma_f32_16x16x32_bf16(ah[mi], bl, acc[mi][ni], 0, 0, 0);
        acc[mi][ni] = __builtin_amdgcn_mfma_f32_16x16x32_bf16(al[mi], bh, acc[mi][ni], 0, 0, 0);
      }
    }
  }
#pragma unroll
  for (int mi = 0; mi < 2; ++mi)
#pragma unroll
    for (int ni = 0; ni < 5; ++ni)
#pragma unroll
      for (int r = 0; r < 4; ++r) {
        int row = m0 + 32 * wr + 16 * mi + quad * 4 + r;
        int col = 80 * wc + 16 * ni + l16;
        part[((size_t)ks * T_ + row) * NC_ + col] = acc[mi][ni][r];
      }
}

// ---------------- reduce partials + LN + rope -> kidx hi/lo; cols 128..159 -> widx ----------------
__launch_bounds__(192)
__global__ void k_kidx_fin(const float* __restrict__ part,
                           const float* __restrict__ gamma, const float* __restrict__ beta,
                           const float* __restrict__ cosT, const float* __restrict__ sinT,
                           unsigned short* __restrict__ kh, unsigned short* __restrict__ kl,
                           float* __restrict__ widx) {
  int t = blockIdx.x;
  int tid = threadIdx.x;
  float y = 0.f;
  if (tid < NC_) {
#pragma unroll
    for (int s = 0; s < KSPLIT_; ++s) y += part[((size_t)s * T_ + t) * NC_ + tid];
  }
  __shared__ float red[128];
  __shared__ float sm2[2];
  __shared__ float yn[128];
  if (tid < 128) red[tid] = y;
  __syncthreads();
  for (int off = 64; off > 0; off >>= 1) {
    if (tid < off) red[tid] += red[tid + off];
    __syncthreads();
  }
  if (tid == 0) sm2[0] = red[0] * (1.f / 128.f);
  __syncthreads();
  float mu = sm2[0];
  if (tid < 128) { float d = y - mu; red[tid] = d * d; }
  __syncthreads();
  for (int off = 64; off > 0; off >>= 1) {
    if (tid < off) red[tid] += red[tid + off];
    __syncthreads();
  }
  if (tid == 0) sm2[1] = red[0] * (1.f / 128.f);
  __syncthreads();
  if (tid < 128) {
    float rstd = rsqrtf(sm2[1] + EPS_);
    yn[tid] = (y - mu) * rstd * gamma[tid] + beta[tid];
  }
  __syncthreads();
  if (tid < 32) {
    int i = tid;
    float co = cosT[t * 32 + i], si = sinT[t * 32 + i];
    float a = yn[i], b = yn[i + 32];
    float v0 = a * co - b * si;
    float v1 = b * co + a * si;
    unsigned short h0 = f2bf(v0);
    kh[(size_t)t * ID_ + i] = h0;
    kl[(size_t)t * ID_ + i] = f2bf(v0 - bf2f(h0));
    unsigned short h1 = f2bf(v1);
    kh[(size_t)t * ID_ + i + 32] = h1;
    kl[(size_t)t * ID_ + i + 32] = f2bf(v1 - bf2f(h1));
  } else if (tid >= 64 && tid < 128) {
    float v = yn[tid];
    unsigned short hb = f2bf(v);
    kh[(size_t)t * ID_ + tid] = hb;
    kl[(size_t)t * ID_ + tid] = f2bf(v - bf2f(hb));
  } else if (tid >= 128 && tid < 160) {
    widx[(size_t)t * 32 + (tid - 128)] = y * WSCALE_;
  }
}

// ---------------- rope kernels ----------------
__global__ void k_rope_q(float* __restrict__ q, const float* __restrict__ cosT,
                         const float* __restrict__ sinT) {
  int idx = blockIdx.x * 256 + threadIdx.x;
  if (idx >= T_ * H_ * 32) return;
  int i = idx & 31;
  int th = idx >> 5;
  int h = th & 15, t = th >> 4;
  float c = cosT[t * 32 + i], s = sinT[t * 32 + i];
  float* p = q + (size_t)t * 3072 + h * 192 + 128 + 2 * i;
  float e = p[0], o = p[1];
  p[0] = e * c - o * s;
  p[1] = o * c + e * s;
}

// fused neox-rope + split-cast to head-major (IH, T, ID) bf16 hi/lo
__launch_bounds__(256)
__global__ void k_qidx_prep(const float* __restrict__ qidx,
                            const float* __restrict__ cosT, const float* __restrict__ sinT,
                            unsigned short* __restrict__ qh, unsigned short* __restrict__ ql) {
  int t = blockIdx.x;
  int tid = threadIdx.x;
#pragma unroll
  for (int m = 0; m < 4; ++m) {
    int e = m * 256 + tid;          // 0..1023
    int h = e >> 5, i = e & 31;
    float c = cosT[t * 32 + i], s = sinT[t * 32 + i];
    const float* p = qidx + (size_t)t * 4096 + h * 128;
    float a = p[i], b = p[i + 32];
    float o0 = a * c - b * s;
    float o1 = b * c + a * s;
    size_t base = ((size_t)h * T_ + t) * 128;
    unsigned short h0 = f2bf(o0);
    qh[base + i] = h0;
    ql[base + i] = f2bf(o0 - bf2f(h0));
    unsigned short h1 = f2bf(o1);
    qh[base + i + 32] = h1;
    ql[base + i + 32] = f2bf(o1 - bf2f(h1));
  }
#pragma unroll
  for (int m = 0; m < 8; ++m) {
    int e = m * 256 + tid;          // 0..2047
    int h = e >> 6, d = 64 + (e & 63);
    float v = qidx[(size_t)t * 4096 + h * 128 + d];
    size_t o = ((size_t)h * T_ + t) * 128 + d;
    unsigned short hb = f2bf(v);
    qh[o] = hb;
    ql[o] = f2bf(v - bf2f(hb));
  }
}

__global__ void k_rope_kpe(const float* __restrict__ kpe, const float* __restrict__ cosT,
                           const float* __restrict__ sinT, float* __restrict__ kper) {
  int idx = blockIdx.x * 256 + threadIdx.x;
  if (idx >= T_ * 32) return;
  int i = idx & 31, t = idx >> 5;
  float c = cosT[idx], s = sinT[idx];
  float e = kpe[(size_t)t * 64 + 2 * i], o = kpe[(size_t)t * 64 + 2 * i + 1];
  kper[(size_t)t * 64 + 2 * i] = e * c - o * s;
  kper[(size_t)t * 64 + 2 * i + 1] = o * c + e * s;
}

// ---------------- indexer scores: split-bf16 3-pass MFMA + reg-prefetch Q ----------------
// K tile staged once; per head h, Q (hi/lo) for h+1 is prefetched into
// registers during h's compute and ds_write'd at the top of the next
// iteration. w values read directly from L2 (no Wsh) => LDS 51KB, 3 blocks/CU.
__launch_bounds__(256)
__global__ void k_scores2(const unsigned short* __restrict__ qh,
                          const unsigned short* __restrict__ ql,
                          const unsigned short* __restrict__ kh,
                          const unsigned short* __restrict__ kl,
                          const float* __restrict__ widx,
                          float* __restrict__ scores) {
  int jb = blockIdx.x, tb = blockIdx.y;
  int t0 = tb * 32, j0 = jb * 64;
  if (j0 > t0 + 31) return;
  __shared__ unsigned short Ksh[64][136];
  __shared__ unsigned short Ksl[64][136];
  __shared__ unsigned short Qsh[32][136];
  __shared__ unsigned short Qsl[32][136];
  int tid = threadIdx.x;
  // stage K tile (64 x 128, hi+lo)
#pragma unroll
  for (int i = 0; i < 4; ++i) {
    int e = i * 256 + tid;
    int r = e >> 4, off = (e & 15) * 8;
    *(uint4*)&Ksh[r][off] = *(const uint4*)&kh[(size_t)(j0 + r) * 128 + off];
    *(uint4*)&Ksl[r][off] = *(const uint4*)&kl[(size_t)(j0 + r) * 128 + off];
  }
  int w = tid >> 6, lane = tid & 63;
  int quad = lane >> 4, l16 = lane & 15;
  int wr = w & 1, wc = w >> 1;
  // per-thread staging slots (fixed): e = i*256+tid
  int re[2], oe[2];
#pragma unroll
  for (int i = 0; i < 2; ++i) {
    int e = i * 256 + tid;
    re[i] = e >> 4;          // 0..31
    oe[i] = (e & 15) * 8;    // 0..120
  }
  // preload Q (h=0) into registers + w for h=0
  uint4 qhr[2], qlr[2];
#pragma unroll
  for (int i = 0; i < 2; ++i) {
    size_t base = ((size_t)t0 + re[i]) * 128 + oe[i];   // h=0
    qhr[i] = *(const uint4*)&qh[base];
    qlr[i] = *(const uint4*)&ql[base];
  }
  float w4[4];
#pragma unroll
  for (int r = 0; r < 4; ++r)
    w4[r] = widx[(size_t)(t0 + 16 * wr + quad * 4 + r) * 32 + 0];

  float s0[4] = {0.f, 0.f, 0.f, 0.f};
  float s1[4] = {0.f, 0.f, 0.f, 0.f};
  for (int h = 0; h < 32; ++h) {
    __syncthreads();  // previous head's compute done reading Qsh
#pragma unroll
    for (int i = 0; i < 2; ++i) {
      *(uint4*)&Qsh[re[i]][oe[i]] = qhr[i];
      *(uint4*)&Qsl[re[i]][oe[i]] = qlr[i];
    }
    // prefetch Q + w for next head (clamped; lands during this head's compute)
    int hn = (h < 31) ? h + 1 : 31;
    uint4 nqh[2], nql[2];
#pragma unroll
    for (int i = 0; i < 2; ++i) {
      size_t base = ((size_t)hn * T_ + t0 + re[i]) * 128 + oe[i];
      nqh[i] = *(const uint4*)&qh[base];
      nql[i] = *(const uint4*)&ql[base];
    }
    float w4n[4];
#pragma unroll
    for (int r = 0; r < 4; ++r)
      w4n[r] = widx[(size_t)(t0 + 16 * wr + quad * 4 + r) * 32 + hn];
    __syncthreads();  // Qsh ready
    f32x4 l0 = {}, l1 = {};
#pragma unroll
    for (int kk = 0; kk < 4; ++kk) {
      bf16x8 ah = *(const bf16x8*)&Qsh[16 * wr + l16][kk * 32 + quad * 8];
      bf16x8 al = *(const bf16x8*)&Qsl[16 * wr + l16][kk * 32 + quad * 8];
      bf16x8 bh0 = *(const bf16x8*)&Ksh[32 * wc + l16][kk * 32 + quad * 8];
      bf16x8 bl0 = *(const bf16x8*)&Ksl[32 * wc + l16][kk * 32 + quad * 8];
      bf16x8 bh1 = *(const bf16x8*)&Ksh[32 * wc + 16 + l16][kk * 32 + quad * 8];
      bf16x8 bl1 = *(const bf16x8*)&Ksl[32 * wc + 16 + l16][kk * 32 + quad * 8];
      l0 = __builtin_amdgcn_mfma_f32_16x16x32_bf16(ah, bh0, l0, 0, 0, 0);
      l0 = __builtin_amdgcn_mfma_f32_16x16x32_bf16(ah, bl0, l0, 0, 0, 0);
      l0 = __builtin_amdgcn_mfma_f32_16x16x32_bf16(al, bh0, l0, 0, 0, 0);
      l1 = __builtin_amdgcn_mfma_f32_16x16x32_bf16(ah, bh1, l1, 0, 0, 0);
      l1 = __builtin_amdgcn_mfma_f32_16x16x32_bf16(ah, bl1, l1, 0, 0, 0);
      l1 = __builtin_amdgcn_mfma_f32_16x16x32_bf16(al, bh1, l1, 0, 0, 0);
    }
#pragma unroll
    for (int r = 0; r < 4; ++r) {
      s0[r] = fmaf(w4[r], fmaxf(l0[r] * ISCALE_, 0.f), s0[r]);
      s1[r] = fmaf(w4[r], fmaxf(l1[r] * ISCALE_, 0.f), s1[r]);
    }
#pragma unroll
    for (int i = 0; i < 2; ++i) { qhr[i] = nqh[i]; qlr[i] = nql[i]; }
#pragma unroll
    for (int r = 0; r < 4; ++r) w4[r] = w4n[r];
  }
#pragma unroll
  for (int r = 0; r < 4; ++r) {
    int row = t0 + 16 * wr + quad * 4 + r;
    scores[(size_t)row * T_ + j0 + 32 * wc + l16] = s0[r];
    scores[(size_t)row * T_ + j0 + 32 * wc + 16 + l16] = s1[r];
  }
}

// ---------------- top-k threshold ----------------
__launch_bounds__(256)
__global__ void k_topk(const float* __restrict__ scores, unsigned int* __restrict__ kth) {
  int t = blockIdx.x;
  int n = t + 1;
  if (n <= TOPK_) {
    if (threadIdx.x == 0) kth[t] = 0u;
    return;
  }
  unsigned int keys[8];
#pragma unroll
  for (int m = 0; m < 8; ++m) {
    int j = threadIdx.x + m * 256;
    keys[m] = (j < n) ? mono(scores[(size_t)t * T_ + j]) : 0u;
  }
  __shared__ int wred[4];
  unsigned int thr = 0u;
  for (int b = 31; b >= 0; --b) {
    unsigned int cand = thr | (1u << b);
    int c = 0;
#pragma unroll
    for (int m = 0; m < 8; ++m) c += (keys[m] >= cand) ? 1 : 0;
    for (int o = 32; o > 0; o >>= 1) c += __shfl_down(c, o, 64);
    if ((threadIdx.x & 63) == 0) wred[threadIdx.x >> 6] = c;
    __syncthreads();
    int total = wred[0] + wred[1] + wred[2] + wred[3];
    if (total >= TOPK_) thr = cand;
    __syncthreads();
  }
  if (threadIdx.x == 0) kth[t] = thr;
}

// ---------------- casts for flash: Qb/Kb (head-major bf16) ----------------
__launch_bounds__(256)
__global__ void k_cast_flash(const float* __restrict__ qbuf, const float* __restrict__ kvb,
                             const float* __restrict__ kper,
                             unsigned short* __restrict__ Qb, unsigned short* __restrict__ Kb) {
  int t = blockIdx.x;
  int tid = threadIdx.x;
#pragma unroll
  for (int i = 0; i < 12; ++i) {
    int e = i * 256 + tid;  // 0..3071
    int h = e / 192, d = e % 192;
    Qb[((size_t)h * T_ + t) * 192 + d] = f2bf(qbuf[(size_t)t * 3072 + e]);
    float kv = (d < 128) ? kvb[(size_t)t * 4096 + h * 256 + d]
                         : kper[(size_t)t * 64 + (d - 128)];
    Kb[((size_t)h * T_ + t) * 192 + d] = f2bf(kv);
  }
}

// ---------------- cast V transposed: Vt[h][d][t] bf16 ----------------
__launch_bounds__(256)
__global__ void k_cast_v(const float* __restrict__ kvb, unsigned short* __restrict__ Vt) {
  __shared__ unsigned short vt[128][137];
  int h = blockIdx.y, t0 = blockIdx.x * 128;
  int tid = threadIdx.x;
#pragma unroll
  for (int i = 0; i < 64; ++i) {
    int e = i * 256 + tid;
    int tl = e >> 7, d = e & 127;
    vt[tl][d] = f2bf(kvb[(size_t)(t0 + tl) * 4096 + h * 256 + 128 + d]);
  }
  __syncthreads();
#pragma unroll
  for (int i = 0; i < 64; ++i) {
    int e = i * 256 + tid;
    int d = e >> 7, tl = e & 127;
    Vt[((size_t)h * 128 + d) * T_ + t0 + tl] = vt[tl][d];
  }
}

// ---------------- MFMA flash attention with top-k mask (flash2 body) ----------------
// k_flash5 = flash2 inner structure verbatim; each block processes the
// complementary tile pair {bx, 63-bx} => constant 65 j-tile iterations/block.
// Grid (32, H): 512 blocks = exactly 2/CU (LDS 43KB, 2 fit).
__launch_bounds__(256)
__global__ void k_flash5(const unsigned short* __restrict__ Qb,
                         const unsigned short* __restrict__ Kb,
                         const unsigned short* __restrict__ Vt,
                         const float* __restrict__ scores,
                         const unsigned int* __restrict__ kth,
                         unsigned short* __restrict__ obf) {
  __shared__ unsigned short Qs[32][200];
  __shared__ unsigned short Ks[32][200];
  __shared__ unsigned short VsT[128][40];
  __shared__ float Ss[32][33];
  __shared__ unsigned short Ps[32][40];
  __shared__ float m_s[32], l_s[32], al_s[32];

  int bx = blockIdx.x, h = blockIdx.y;
  int tid = threadIdx.x;
  int w = tid >> 6, lane = tid & 63;
  int quad = lane >> 4, l16 = lane & 15;
  int wr = w & 1, wc = w >> 1;

  int srow = tid >> 3;
  int c8 = tid & 7;

  for (int half = 0; half < 2; ++half) {
    int tile = (half == 0) ? bx : (63 - bx);   // 0..63
    int t0 = tile * 32;
    __syncthreads();  // protect m_s/l_s reinit vs prior half's epilogue reads

    // stage Q once (32 x 192 bf16)
#pragma unroll
    for (int i = 0; i < 3; ++i) {
      int c = i * 256 + tid;
      int row = c / 24, off = (c % 24) * 8;
      *(uint4*)&Qs[row][off] =
          *(const uint4*)&Qb[((size_t)h * T_ + t0 + row) * 192 + off];
    }
    if (tid < 32) { m_s[tid] = -INFINITY; l_s[tid] = 0.f; }

    f32x4 Of[4] = {};
    int ig = t0 + srow;

    int njt = tile + 1;
    for (int jt = 0; jt < njt; ++jt) {
      int j0 = jt * 32;
      __syncthreads();
#pragma unroll
      for (int i = 0; i < 3; ++i) {
        int c = i * 256 + tid;
        int row = c / 24, off = (c % 24) * 8;
        *(uint4*)&Ks[row][off] =
            *(const uint4*)&Kb[((size_t)h * T_ + j0 + row) * 192 + off];
      }
#pragma unroll
      for (int i = 0; i < 2; ++i) {
        int c = i * 256 + tid;
        int d = c >> 2, off = (c & 3) * 8;
        *(uint4*)&VsT[d][off] =
            *(const uint4*)&Vt[((size_t)h * 128 + d) * T_ + j0 + off];
      }
      __syncthreads();

      f32x4 Sacc = {};
#pragma unroll
      for (int kk = 0; kk < 6; ++kk) {
        bf16x8 a = *(const bf16x8*)&Qs[16 * wr + l16][kk * 32 + quad * 8];
        bf16x8 b = *(const bf16x8*)&Ks[16 * wc + l16][kk * 32 + quad * 8];
        Sacc = __builtin_amdgcn_mfma_f32_16x16x32_bf16(a, b, Sacc, 0, 0, 0);
      }
#pragma unroll
      for (int r = 0; r < 4; ++r)
        Ss[16 * wr + quad * 4 + r][16 * wc + l16] = Sacc[r];
      __syncthreads();

      float mold = m_s[srow];
      unsigned int kt = kth[ig];
      float4 s4 = *(const float4*)(scores + (size_t)ig * T_ + j0 + 4 * c8);
      float sv[4] = {s4.x, s4.y, s4.z, s4.w};
      float v[4];
#pragma unroll
      for (int c = 0; c < 4; ++c) {
        int jg = j0 + 4 * c8 + c;
        float sc = Ss[srow][4 * c8 + c];
        bool ok = (jg <= ig) && (mono(sv[c]) >= kt);
        v[c] = ok ? sc * SCALE_ : -INFINITY;
      }
      float tmax = fmaxf(fmaxf(v[0], v[1]), fmaxf(v[2], v[3]));
#pragma unroll
      for (int o = 1; o < 8; o <<= 1) tmax = fmaxf(tmax, __shfl_xor(tmax, o, 8));
      float mn = fmaxf(mold, tmax);
      float alpha = (mold == -INFINITY) ? 0.f : expf(mold - mn);
      float p[4], psum = 0.f;
#pragma unroll
      for (int c = 0; c < 4; ++c) {
        p[c] = (v[c] == -INFINITY) ? 0.f : expf(v[c] - mn);
        psum += p[c];
      }
#pragma unroll
      for (int o = 1; o < 8; o <<= 1) psum += __shfl_xor(psum, o, 8);
      if (c8 == 0) {
        m_s[srow] = mn;
        al_s[srow] = alpha;
        l_s[srow] = alpha * l_s[srow] + psum;
      }
#pragma unroll
      for (int c = 0; c < 4; ++c) Ps[srow][4 * c8 + c] = f2bf(p[c]);
      __syncthreads();

      float arow[4];
#pragma unroll
      for (int r = 0; r < 4; ++r) arow[r] = al_s[16 * wr + quad * 4 + r];
      bf16x8 pa = *(const bf16x8*)&Ps[16 * wr + l16][quad * 8];
#pragma unroll
      for (int i = 0; i < 4; ++i) {
#pragma unroll
        for (int r = 0; r < 4; ++r) Of[i][r] *= arow[r];
        bf16x8 vb = *(const bf16x8*)&VsT[16 * (4 * wc + i) + l16][quad * 8];
        Of[i] = __builtin_amdgcn_mfma_f32_16x16x32_bf16(pa, vb, Of[i], 0, 0, 0);
      }
    }

    // epilogue: normalize and write bf16 O (t, h*128+col)
    float linv[4];
#pragma unroll
    for (int r = 0; r < 4; ++r) linv[r] = 1.f / l_s[16 * wr + quad * 4 + r];
#pragma unroll
    for (int i = 0; i < 4; ++i) {
#pragma unroll
      for (int r = 0; r < 4; ++r) {
        int row = t0 + 16 * wr + quad * 4 + r;
        int col = 16 * (4 * wc + i) + l16;
        obf[(size_t)row * 2048 + h * 128 + col] = f2bf(Of[i][r] * linv[r]);
      }
    }
  }
}

}  // namespace

extern "C" void kernel_launch(void* const* d_in, const int* in_sizes, int n_in,
                              void* d_out, int out_size, void* d_ws, size_t ws_size,
                              hipStream_t stream) {
  (void)in_sizes; (void)n_in; (void)out_size; (void)ws_size;
  const int*   positions = (const int*)d_in[0];
  const float* hidden  = (const float*)d_in[1];
  const float* q_c     = (const float*)d_in[2];
  const float* kv_c    = (const float*)d_in[3];
  const float* k_pe    = (const float*)d_in[4];
  const float* q_ln    = (const float*)d_in[5];
  const float* kv_ln   = (const float*)d_in[6];
  const float* Wq_b    = (const float*)d_in[7];
  const float* Wkv_b   = (const float*)d_in[8];
  const float* Wo      = (const float*)d_in[9];
  const float* Wiq     = (const float*)d_in[10];
  const float* Wik     = (const float*)d_in[11];
  const float* ik_g    = (const float*)d_in[12];
  const float* ik_b    = (const float*)d_in[13];
  const float* Ww      = (const float*)d_in[14];
  float* out = (float*)d_out;

  float* ws = (float*)d_ws;
  size_t off = 0;
  float* cosT = ws + off; off += (size_t)T_ * 32;
  float* sinT = ws + off; off += (size_t)T_ * 32;
  float* qcn  = ws + off; off += (size_t)T_ * QLR_;   // slot reused: qcn_lo (bf16)
  float* kvn  = ws + off; off += (size_t)T_ * KVLR_;  // slot reused: kidx hi/lo (bf16)
  float* qbuf = ws + off; off += (size_t)T_ * H_ * 192;  // early overlay: Wiqt hi/lo
  float* kvb  = ws + off; off += (size_t)T_ * H_ * 256;
  float* qidx = ws + off; off += (size_t)T_ * 4096;   // f32; later overlay: Qb/Kb/obf
  float* kidx = ws + off; off += (size_t)T_ * ID_;    // unused (layout stability)
  float* widx = ws + off; off += (size_t)T_ * IH_;
  float* kper = ws + off; off += (size_t)T_ * 64;
  float* scores = ws + off; off += (size_t)T_ * T_;   // early: Wqt+Wkvt, then hgemm partials
  unsigned int* kth = (unsigned int*)(ws + off); off += T_;
  unsigned short* qcn_bf = (unsigned short*)(ws + off); off += (size_t)T_ * QLR_ / 2;
  unsigned short* kvn_bf = (unsigned short*)(ws + off); off += (size_t)T_ * KVLR_ / 2;
  unsigned short* Wot = (unsigned short*)(ws + off); off += (size_t)HID_ * 2048 / 2;
  unsigned short* Vt  = (unsigned short*)(ws + off); off += (size_t)H_ * 128 * T_ / 2;
  unsigned short* qidx_h = (unsigned short*)(ws + off); off += (size_t)T_ * 4096 / 2;
  unsigned short* qidx_l = (unsigned short*)(ws + off); off += (size_t)T_ * 4096 / 2;
  // combined [Wik|Ww]^T bf16 hi/lo (160 x 7168)
  unsigned short* Bikw_h = (unsigned short*)(ws + off); off += (size_t)NC_ * HID_ / 2;
  unsigned short* Bikw_l = (unsigned short*)(ws + off); off += (size_t)NC_ * HID_ / 2;
  (void)kidx;

  // overlays
  unsigned short* Wqt  = (unsigned short*)scores;                  // 3072x1536 bf16
  unsigned short* Wkvt = Wqt + (size_t)3072 * 1536;                // 4096x512 bf16
  float* hpart = scores;                                           // [KSPLIT][T][160] f32
  unsigned short* Qb   = (unsigned short*)qidx;                    // (16,2048,192)
  unsigned short* Kb   = Qb + (size_t)H_ * T_ * 192;               // (16,2048,192)
  unsigned short* obf  = Kb + (size_t)H_ * T_ * 192;               // (2048,2048)
  unsigned short* qcn_lo = (unsigned short*)qcn;                   // T x 1536 bf16
  unsigned short* kidx_h = (unsigned short*)kvn;                   // T x 128 bf16
  unsigned short* kidx_l = kidx_h + (size_t)T_ * ID_;
  unsigned short* Wiqt_h = (unsigned short*)qbuf;                  // 4096x1536 bf16 (dead before Wq GEMM)
  unsigned short* Wiqt_l = Wiqt_h + (size_t)4096 * QLR_;

  k_tables<<<dim3(T_ * 32 / 256), dim3(256), 0, stream>>>(positions, cosT, sinT);
  k_rms<QLR_><<<dim3(T_), dim3(256), 0, stream>>>(q_c, q_ln, qcn_bf, qcn_lo);
  k_rms<KVLR_><<<dim3(T_), dim3(256), 0, stream>>>(kv_c, kv_ln, kvn_bf, nullptr);
  // indexer qidx GEMM first (Wiqt overlays qbuf, which the Wq GEMM overwrites later)
  k_tc2<<<dim3(4096 / 64, QLR_ / 64), dim3(256), 0, stream>>>(Wiq, Wiqt_h, Wiqt_l, QLR_, 4096);
  k_gemm3<<<dim3(4096 / 128, T_ / 128), dim3(256), 0, stream>>>(qcn_bf, qcn_lo, Wiqt_h, Wiqt_l,
                                                                qidx, T_, 4096, QLR_);
  k_qidx_prep<<<dim3(T_), dim3(256), 0, stream>>>(qidx, cosT, sinT, qidx_h, qidx_l);
  // attention-path weight casts + GEMMs (consume Wqt/Wkvt before hgemm partials overwrite)
  k_tc<<<dim3(3072 / 64, QLR_ / 64), dim3(256), 0, stream>>>(Wq_b, Wqt, QLR_, 3072);
  k_tc<<<dim3(4096 / 64, KVLR_ / 64), dim3(256), 0, stream>>>(Wkv_b, Wkvt, KVLR_, 4096);
  k_tc<<<dim3(HID_ / 64, 2048 / 64), dim3(256), 0, stream>>>(Wo, Wot, 2048, HID_);
  k_tc2w<<<dim3(HID_ / 64, 3), dim3(256), 0, stream>>>(Wik, Ww, Bikw_h, Bikw_l);
  k_gemm_bf<<<dim3(3072 / 128, T_ / 128), dim3(256), 0, stream>>>(qcn_bf, Wqt, qbuf, T_, 3072, QLR_);
  k_rope_q<<<dim3(T_ * H_ * 32 / 256), dim3(256), 0, stream>>>(qbuf, cosT, sinT);
  k_gemm_bf<<<dim3(4096 / 128, T_ / 128), dim3(256), 0, stream>>>(kvn_bf, Wkvt, kvb, T_, 4096, KVLR_);
  // fused hidden GEMM (partials into scores region; Wqt/Wkvt now dead)
  k_hgemm<<<dim3(KSPLIT_, T_ / 64), dim3(256), 0, stream>>>(hidden, Bikw_h, Bikw_l, hpart);
  k_kidx_fin<<<dim3(T_), dim3(192), 0, stream>>>(hpart, ik_g, ik_b, cosT, sinT,
                                                 kidx_h, kidx_l, widx);
  k_rope_kpe<<<dim3(T_ * 32 / 256), dim3(256), 0, stream>>>(k_pe, cosT, sinT, kper);
  // scores AFTER fin (scores region overwrites hgemm partials)
  k_scores2<<<dim3(T_ / 64, T_ / 32), dim3(256), 0, stream>>>(qidx_h, qidx_l, kidx_h, kidx_l,
                                                              widx, scores);
  k_topk<<<dim3(T_), dim3(256), 0, stream>>>(scores, kth);
  // casts AFTER k_qidx_prep (Qb/Kb/obf overlay the dead f32 qidx)
  k_cast_flash<<<dim3(T_), dim3(256), 0, stream>>>(qbuf, kvb, kper, Qb, Kb);
  k_cast_v<<<dim3(T_ / 128, H_), dim3(256), 0, stream>>>(kvb, Vt);
  k_flash5<<<dim3(32, H_), dim3(256), 0, stream>>>(Qb, Kb, Vt, scores, kth, obf);
  k_gemm_bf<<<dim3(HID_ / 128, T_ / 128), dim3(256), 0, stream>>>(obf, Wot, out, T_, HID_, 2048);
}

// Round 12
// 869.846 us; speedup vs baseline: 1.4317x; 1.4317x over previous
//
#include <hip/hip_runtime.h>
#include <hip/hip_bf16.h>
#include <math.h>

// DeepseekV32 MLA attention + lightning indexer, MI355X (gfx950).
// Round 14: k_scores2's register-prefetch spilled to scratch (VGPR 88->68,
// WRITE_SIZE 8.4MB->302MB => 520us). Revert the prefetch; keep only the safe
// half: drop Wsh from LDS (w read direct from L2 at the accumulate site).
// k_scores3 = round-10 k_scores_mfma body verbatim, LDS 56.8->51KB = 3 blk/CU.

namespace {

constexpr int T_    = 2048;
constexpr int HID_  = 7168;
constexpr int H_    = 16;
constexpr int QLR_  = 1536;
constexpr int KVLR_ = 512;
constexpr int IH_   = 32;
constexpr int ID_   = 128;
constexpr int TOPK_ = 512;
constexpr float EPS_    = 1e-6f;
constexpr float SCALE_  = 0.07216878364870322f;   // (128+64)^-0.5
constexpr float ISCALE_ = 0.08838834764831845f;   // 128^-0.5
constexpr float WSCALE_ = 0.17677669529663687f;   // 32^-0.5

// hidden GEMM: split-K config
constexpr int KSPLIT_ = 8;
constexpr int KC_     = HID_ / KSPLIT_;  // 896 = 28 steps of 32
constexpr int NC_     = 160;             // 128 (Wik) + 32 (Ww)

typedef __attribute__((ext_vector_type(8))) short bf16x8;
typedef __attribute__((ext_vector_type(4))) float f32x4;

__device__ __forceinline__ unsigned int mono(float x) {
  unsigned int u = __float_as_uint(x);
  return (u & 0x80000000u) ? ~u : (u | 0x80000000u);
}

__device__ __forceinline__ unsigned short f2bf(float x) {
  unsigned int u = __float_as_uint(x);
  u += 0x7FFFu + ((u >> 16) & 1u);
  return (unsigned short)(u >> 16);
}

__device__ __forceinline__ float bf2f(unsigned short h) {
  return __uint_as_float((unsigned int)h << 16);
}

// ---------------- rope tables ----------------
__global__ void k_tables(const int* __restrict__ pos, float* __restrict__ cosT,
                         float* __restrict__ sinT) {
  int idx = blockIdx.x * 256 + threadIdx.x;
  if (idx >= T_ * 32) return;
  int t = idx >> 5, i = idx & 31;
  float invf = (float)pow(10000.0, -(double)i / 32.0);
  float ang = (float)pos[t] * invf;
  cosT[idx] = cosf(ang);
  sinT[idx] = sinf(ang);
}

// ---------------- rmsnorm: bf16 hi (+ optional lo residual) ----------------
template <int N>
__launch_bounds__(256)
__global__ void k_rms(const float* __restrict__ x, const float* __restrict__ w,
                      unsigned short* __restrict__ yhi, unsigned short* __restrict__ ylo) {
  int t = blockIdx.x;
  const float* xr = x + (size_t)t * N;
  float ss = 0.f;
  for (int c = threadIdx.x; c < N; c += 256) { float v = xr[c]; ss += v * v; }
  __shared__ float red[256];
  red[threadIdx.x] = ss;
  __syncthreads();
  for (int off = 128; off > 0; off >>= 1) {
    if (threadIdx.x < off) red[threadIdx.x] += red[threadIdx.x + off];
    __syncthreads();
  }
  float sc = rsqrtf(red[0] * (1.f / N) + EPS_);
  unsigned short* yhr = yhi + (size_t)t * N;
  unsigned short* ylr = ylo ? ylo + (size_t)t * N : nullptr;
  for (int c = threadIdx.x; c < N; c += 256) {
    float v = xr[c] * sc * w[c];
    unsigned short hb = f2bf(v);
    yhr[c] = hb;
    if (ylr) ylr[c] = f2bf(v - bf2f(hb));
  }
}

// ---------------- transpose-cast: W (K x N, f32) -> Wt (N x K, bf16) ----------------
__launch_bounds__(256)
__global__ void k_tc(const float* __restrict__ W, unsigned short* __restrict__ Wt,
                     int K, int N) {
  __shared__ float tile[64][65];
  int k0 = blockIdx.y * 64, n0 = blockIdx.x * 64;
  int tid = threadIdx.x;
#pragma unroll
  for (int i = 0; i < 16; ++i) {
    int e = i * 256 + tid;
    int r = e >> 6, c = e & 63;
    tile[r][c] = W[(size_t)(k0 + r) * N + n0 + c];
  }
  __syncthreads();
#pragma unroll
  for (int i = 0; i < 16; ++i) {
    int e = i * 256 + tid;
    int r = e >> 6, c = e & 63;
    Wt[(size_t)(n0 + r) * K + k0 + c] = f2bf(tile[c][r]);
  }
}

// ---------------- transpose + split-cast: W (K x N, f32) -> Wt_hi/Wt_lo (N x K) ----------------
__launch_bounds__(256)
__global__ void k_tc2(const float* __restrict__ W, unsigned short* __restrict__ Wth,
                      unsigned short* __restrict__ Wtl, int K, int N) {
  __shared__ float tile[64][65];
  int k0 = blockIdx.y * 64, n0 = blockIdx.x * 64;
  int tid = threadIdx.x;
#pragma unroll
  for (int i = 0; i < 16; ++i) {
    int e = i * 256 + tid;
    int r = e >> 6, c = e & 63;
    tile[r][c] = W[(size_t)(k0 + r) * N + n0 + c];
  }
  __syncthreads();
#pragma unroll
  for (int i = 0; i < 16; ++i) {
    int e = i * 256 + tid;
    int r = e >> 6, c = e & 63;
    float v = tile[c][r];
    unsigned short hb = f2bf(v);
    size_t o = (size_t)(n0 + r) * K + k0 + c;
    Wth[o] = hb;
    Wtl[o] = f2bf(v - bf2f(hb));
  }
}

// ---------------- combined [Wik | Ww] transpose + split-cast -> (160 x 7168) hi/lo ----------------
__launch_bounds__(256)
__global__ void k_tc2w(const float* __restrict__ Wik, const float* __restrict__ Ww,
                       unsigned short* __restrict__ Bth, unsigned short* __restrict__ Btl) {
  __shared__ float tile[64][65];
  int k0 = blockIdx.x * 64;
  int ny = blockIdx.y;              // 0,1: Wik cols; 2: Ww cols (32)
  int ncols = (ny == 2) ? 32 : 64;
  int tid = threadIdx.x;
#pragma unroll
  for (int i = 0; i < 16; ++i) {
    int e = i * 256 + tid;
    int r = e >> 6, c = e & 63;
    if (c < ncols)
      tile[r][c] = (ny == 2) ? Ww[(size_t)(k0 + r) * 32 + c]
                             : Wik[(size_t)(k0 + r) * 128 + ny * 64 + c];
  }
  __syncthreads();
#pragma unroll
  for (int i = 0; i < 16; ++i) {
    int e = i * 256 + tid;
    int r = e >> 6, c = e & 63;
    if (r < ncols) {
      float v = tile[c][r];
      unsigned short hb = f2bf(v);
      size_t o = (size_t)(ny * 64 + r) * HID_ + k0 + c;
      Bth[o] = hb;
      Btl[o] = f2bf(v - bf2f(hb));
    }
  }
}

// ---------------- bf16 MFMA GEMM: C(M,N) f32 = A(M,K) bf16 @ Bt(N,K) bf16 ----------------
__launch_bounds__(256)
__global__ void k_gemm_bf(const unsigned short* __restrict__ A,
                          const unsigned short* __restrict__ Bt,
                          float* __restrict__ C, int M, int N, int K) {
  __shared__ unsigned short As[128][40];
  __shared__ unsigned short Bs[128][40];
  int m0 = blockIdx.y * 128, n0 = blockIdx.x * 128;
  int tid = threadIdx.x;
  int w = tid >> 6, lane = tid & 63;
  int quad = lane >> 4, l16 = lane & 15;
  int wr = w & 1, wc = w >> 1;
  f32x4 acc[4][4] = {};
  for (int k0 = 0; k0 < K; k0 += 32) {
    __syncthreads();
#pragma unroll
    for (int i = 0; i < 2; ++i) {
      int c = i * 256 + tid;
      int row = c >> 2, off = (c & 3) * 8;
      *(uint4*)&As[row][off] = *(const uint4*)&A[(size_t)(m0 + row) * K + k0 + off];
      *(uint4*)&Bs[row][off] = *(const uint4*)&Bt[(size_t)(n0 + row) * K + k0 + off];
    }
    __syncthreads();
    bf16x8 a[4], b[4];
#pragma unroll
    for (int mi = 0; mi < 4; ++mi) a[mi] = *(const bf16x8*)&As[64 * wr + 16 * mi + l16][quad * 8];
#pragma unroll
    for (int ni = 0; ni < 4; ++ni) b[ni] = *(const bf16x8*)&Bs[64 * wc + 16 * ni + l16][quad * 8];
#pragma unroll
    for (int mi = 0; mi < 4; ++mi)
#pragma unroll
      for (int ni = 0; ni < 4; ++ni)
        acc[mi][ni] = __builtin_amdgcn_mfma_f32_16x16x32_bf16(a[mi], b[ni], acc[mi][ni], 0, 0, 0);
  }
#pragma unroll
  for (int mi = 0; mi < 4; ++mi)
#pragma unroll
    for (int ni = 0; ni < 4; ++ni)
#pragma unroll
      for (int r = 0; r < 4; ++r) {
        int row = m0 + 64 * wr + 16 * mi + quad * 4 + r;
        int col = n0 + 64 * wc + 16 * ni + l16;
        C[(size_t)row * N + col] = acc[mi][ni][r];
      }
}

// ---------------- split-bf16 3-pass GEMM: C f32 = (Ah+Al)(M,K) @ (Bh+Bl)t(N,K) ----------------
__launch_bounds__(256)
__global__ void k_gemm3(const unsigned short* __restrict__ Ah,
                        const unsigned short* __restrict__ Al,
                        const unsigned short* __restrict__ Bth,
                        const unsigned short* __restrict__ Btl,
                        float* __restrict__ C, int M, int N, int K) {
  __shared__ unsigned short Ash[128][40];
  __shared__ unsigned short Asl[128][40];
  __shared__ unsigned short Bsh[128][40];
  __shared__ unsigned short Bsl[128][40];
  int m0 = blockIdx.y * 128, n0 = blockIdx.x * 128;
  int tid = threadIdx.x;
  int w = tid >> 6, lane = tid & 63;
  int quad = lane >> 4, l16 = lane & 15;
  int wr = w & 1, wc = w >> 1;
  f32x4 acc[4][4] = {};
  for (int k0 = 0; k0 < K; k0 += 32) {
    __syncthreads();
#pragma unroll
    for (int i = 0; i < 2; ++i) {
      int c = i * 256 + tid;
      int row = c >> 2, off = (c & 3) * 8;
      *(uint4*)&Ash[row][off] = *(const uint4*)&Ah[(size_t)(m0 + row) * K + k0 + off];
      *(uint4*)&Asl[row][off] = *(const uint4*)&Al[(size_t)(m0 + row) * K + k0 + off];
      *(uint4*)&Bsh[row][off] = *(const uint4*)&Bth[(size_t)(n0 + row) * K + k0 + off];
      *(uint4*)&Bsl[row][off] = *(const uint4*)&Btl[(size_t)(n0 + row) * K + k0 + off];
    }
    __syncthreads();
    bf16x8 ah[4], al[4];
#pragma unroll
    for (int mi = 0; mi < 4; ++mi) {
      ah[mi] = *(const bf16x8*)&Ash[64 * wr + 16 * mi + l16][quad * 8];
      al[mi] = *(const bf16x8*)&Asl[64 * wr + 16 * mi + l16][quad * 8];
    }
#pragma unroll
    for (int nh = 0; nh < 2; ++nh) {
      bf16x8 bh[2], bl[2];
#pragma unroll
      for (int nj = 0; nj < 2; ++nj) {
        int nrow = 64 * wc + 16 * (2 * nh + nj) + l16;
        bh[nj] = *(const bf16x8*)&Bsh[nrow][quad * 8];
        bl[nj] = *(const bf16x8*)&Bsl[nrow][quad * 8];
      }
#pragma unroll
      for (int mi = 0; mi < 4; ++mi)
#pragma unroll
        for (int nj = 0; nj < 2; ++nj) {
          int ni = 2 * nh + nj;
          acc[mi][ni] = __builtin_amdgcn_mfma_f32_16x16x32_bf16(ah[mi], bh[nj], acc[mi][ni], 0, 0, 0);
          acc[mi][ni] = __builtin_amdgcn_mfma_f32_16x16x32_bf16(ah[mi], bl[nj], acc[mi][ni], 0, 0, 0);
          acc[mi][ni] = __builtin_amdgcn_mfma_f32_16x16x32_bf16(al[mi], bh[nj], acc[mi][ni], 0, 0, 0);
        }
    }
  }
#pragma unroll
  for (int mi = 0; mi < 4; ++mi)
#pragma unroll
    for (int ni = 0; ni < 4; ++ni)
#pragma unroll
      for (int r = 0; r < 4; ++r) {
        int row = m0 + 64 * wr + 16 * mi + quad * 4 + r;
        int col = n0 + 64 * wc + 16 * ni + l16;
        C[(size_t)row * N + col] = acc[mi][ni][r];
      }
}

// ---------------- fused hidden GEMM: part[s] = hidden(64-tile, Kc) @ [Wik|Ww]^T ----------------
__launch_bounds__(256)
__global__ void k_hgemm(const float* __restrict__ hidden,
                        const unsigned short* __restrict__ Bth,
                        const unsigned short* __restrict__ Btl,
                        float* __restrict__ part) {
  __shared__ unsigned short Ash[64][40];
  __shared__ unsigned short Asl[64][40];
  __shared__ unsigned short Bsh[NC_][40];
  __shared__ unsigned short Bsl[NC_][40];
  int ks = blockIdx.x, m0 = blockIdx.y * 64;
  int kc0 = ks * KC_;
  int tid = threadIdx.x;
  int w = tid >> 6, lane = tid & 63;
  int quad = lane >> 4, l16 = lane & 15;
  int wr = w & 1, wc = w >> 1;   // wave: 32 rows x 80 cols
  f32x4 acc[2][5] = {};
  for (int s = 0; s < KC_ / 32; ++s) {
    int k0 = kc0 + s * 32;
    __syncthreads();
#pragma unroll
    for (int i = 0; i < 2; ++i) {
      int c = i * 256 + tid;          // 0..511
      int row = c >> 3, off = (c & 7) * 4;
      float4 v = *(const float4*)&hidden[(size_t)(m0 + row) * HID_ + k0 + off];
      ushort4 hv, lv;
      hv.x = f2bf(v.x); lv.x = f2bf(v.x - bf2f(hv.x));
      hv.y = f2bf(v.y); lv.y = f2bf(v.y - bf2f(hv.y));
      hv.z = f2bf(v.z); lv.z = f2bf(v.z - bf2f(hv.z));
      hv.w = f2bf(v.w); lv.w = f2bf(v.w - bf2f(hv.w));
      *(ushort4*)&Ash[row][off] = hv;
      *(ushort4*)&Asl[row][off] = lv;
    }
#pragma unroll
    for (int i = 0; i < 3; ++i) {
      int c = i * 256 + tid;          // 0..639 valid
      if (c < NC_ * 4) {
        int row = c >> 2, off = (c & 3) * 8;
        *(uint4*)&Bsh[row][off] = *(const uint4*)&Bth[(size_t)row * HID_ + k0 + off];
        *(uint4*)&Bsl[row][off] = *(const uint4*)&Btl[(size_t)row * HID_ + k0 + off];
      }
    }
    __syncthreads();
    bf16x8 ah[2], al[2];
#pragma unroll
    for (int mi = 0; mi < 2; ++mi) {
      ah[mi] = *(const bf16x8*)&Ash[32 * wr + 16 * mi + l16][quad * 8];
      al[mi] = *(const bf16x8*)&Asl[32 * wr + 16 * mi + l16][quad * 8];
    }
#pragma unroll
    for (int ni = 0; ni < 5; ++ni) {
      int nrow = 80 * wc + 16 * ni + l16;
      bf16x8 bh = *(const bf16x8*)&Bsh[nrow][quad * 8];
      bf16x8 bl = *(const bf16x8*)&Bsl[nrow][quad * 8];
#pragma unroll
      for (int mi = 0; mi < 2; ++mi) {
        acc[mi][ni] = __builtin_amdgcn_mfma_f32_16x16x32_bf16(ah[mi], bh, acc[mi][ni], 0, 0, 0);
        acc[mi][ni] = __builtin_amdgcn_mfma_f32_16x16x32_bf16(ah[mi], bl, acc[mi][ni], 0, 0, 0);
        acc[mi][ni] = __builtin_amdgcn_mfma_f32_16x16x32_bf16(al[mi], bh, acc[mi][ni], 0, 0, 0);
      }
    }
  }
#pragma unroll
  for (int mi = 0; mi < 2; ++mi)
#pragma unroll
    for (int ni = 0; ni < 5; ++ni)
#pragma unroll
      for (int r = 0; r < 4; ++r) {
        int row = m0 + 32 * wr + 16 * mi + quad * 4 + r;
        int col = 80 * wc + 16 * ni + l16;
        part[((size_t)ks * T_ + row) * NC_ + col] = acc[mi][ni][r];
      }
}

// ---------------- reduce partials + LN + rope -> kidx hi/lo; cols 128..159 -> widx ----------------
__launch_bounds__(192)
__global__ void k_kidx_fin(const float* __restrict__ part,
                           const float* __restrict__ gamma, const float* __restrict__ beta,
                           const float* __restrict__ cosT, const float* __restrict__ sinT,
                           unsigned short* __restrict__ kh, unsigned short* __restrict__ kl,
                           float* __restrict__ widx) {
  int t = blockIdx.x;
  int tid = threadIdx.x;
  float y = 0.f;
  if (tid < NC_) {
#pragma unroll
    for (int s = 0; s < KSPLIT_; ++s) y += part[((size_t)s * T_ + t) * NC_ + tid];
  }
  __shared__ float red[128];
  __shared__ float sm2[2];
  __shared__ float yn[128];
  if (tid < 128) red[tid] = y;
  __syncthreads();
  for (int off = 64; off > 0; off >>= 1) {
    if (tid < off) red[tid] += red[tid + off];
    __syncthreads();
  }
  if (tid == 0) sm2[0] = red[0] * (1.f / 128.f);
  __syncthreads();
  float mu = sm2[0];
  if (tid < 128) { float d = y - mu; red[tid] = d * d; }
  __syncthreads();
  for (int off = 64; off > 0; off >>= 1) {
    if (tid < off) red[tid] += red[tid + off];
    __syncthreads();
  }
  if (tid == 0) sm2[1] = red[0] * (1.f / 128.f);
  __syncthreads();
  if (tid < 128) {
    float rstd = rsqrtf(sm2[1] + EPS_);
    yn[tid] = (y - mu) * rstd * gamma[tid] + beta[tid];
  }
  __syncthreads();
  if (tid < 32) {
    int i = tid;
    float co = cosT[t * 32 + i], si = sinT[t * 32 + i];
    float a = yn[i], b = yn[i + 32];
    float v0 = a * co - b * si;
    float v1 = b * co + a * si;
    unsigned short h0 = f2bf(v0);
    kh[(size_t)t * ID_ + i] = h0;
    kl[(size_t)t * ID_ + i] = f2bf(v0 - bf2f(h0));
    unsigned short h1 = f2bf(v1);
    kh[(size_t)t * ID_ + i + 32] = h1;
    kl[(size_t)t * ID_ + i + 32] = f2bf(v1 - bf2f(h1));
  } else if (tid >= 64 && tid < 128) {
    float v = yn[tid];
    unsigned short hb = f2bf(v);
    kh[(size_t)t * ID_ + tid] = hb;
    kl[(size_t)t * ID_ + tid] = f2bf(v - bf2f(hb));
  } else if (tid >= 128 && tid < 160) {
    widx[(size_t)t * 32 + (tid - 128)] = y * WSCALE_;
  }
}

// ---------------- rope kernels ----------------
__global__ void k_rope_q(float* __restrict__ q, const float* __restrict__ cosT,
                         const float* __restrict__ sinT) {
  int idx = blockIdx.x * 256 + threadIdx.x;
  if (idx >= T_ * H_ * 32) return;
  int i = idx & 31;
  int th = idx >> 5;
  int h = th & 15, t = th >> 4;
  float c = cosT[t * 32 + i], s = sinT[t * 32 + i];
  float* p = q + (size_t)t * 3072 + h * 192 + 128 + 2 * i;
  float e = p[0], o = p[1];
  p[0] = e * c - o * s;
  p[1] = o * c + e * s;
}

// fused neox-rope + split-cast to head-major (IH, T, ID) bf16 hi/lo
__launch_bounds__(256)
__global__ void k_qidx_prep(const float* __restrict__ qidx,
                            const float* __restrict__ cosT, const float* __restrict__ sinT,
                            unsigned short* __restrict__ qh, unsigned short* __restrict__ ql) {
  int t = blockIdx.x;
  int tid = threadIdx.x;
#pragma unroll
  for (int m = 0; m < 4; ++m) {
    int e = m * 256 + tid;          // 0..1023
    int h = e >> 5, i = e & 31;
    float c = cosT[t * 32 + i], s = sinT[t * 32 + i];
    const float* p = qidx + (size_t)t * 4096 + h * 128;
    float a = p[i], b = p[i + 32];
    float o0 = a * c - b * s;
    float o1 = b * c + a * s;
    size_t base = ((size_t)h * T_ + t) * 128;
    unsigned short h0 = f2bf(o0);
    qh[base + i] = h0;
    ql[base + i] = f2bf(o0 - bf2f(h0));
    unsigned short h1 = f2bf(o1);
    qh[base + i + 32] = h1;
    ql[base + i + 32] = f2bf(o1 - bf2f(h1));
  }
#pragma unroll
  for (int m = 0; m < 8; ++m) {
    int e = m * 256 + tid;          // 0..2047
    int h = e >> 6, d = 64 + (e & 63);
    float v = qidx[(size_t)t * 4096 + h * 128 + d];
    size_t o = ((size_t)h * T_ + t) * 128 + d;
    unsigned short hb = f2bf(v);
    qh[o] = hb;
    ql[o] = f2bf(v - bf2f(hb));
  }
}

__global__ void k_rope_kpe(const float* __restrict__ kpe, const float* __restrict__ cosT,
                           const float* __restrict__ sinT, float* __restrict__ kper) {
  int idx = blockIdx.x * 256 + threadIdx.x;
  if (idx >= T_ * 32) return;
  int i = idx & 31, t = idx >> 5;
  float c = cosT[idx], s = sinT[idx];
  float e = kpe[(size_t)t * 64 + 2 * i], o = kpe[(size_t)t * 64 + 2 * i + 1];
  kper[(size_t)t * 64 + 2 * i] = e * c - o * s;
  kper[(size_t)t * 64 + 2 * i + 1] = o * c + e * s;
}

// ---------------- indexer scores via split-bf16 3-pass MFMA (round-10 body, no Wsh) ----------------
__launch_bounds__(256)
__global__ void k_scores3(const unsigned short* __restrict__ qh,
                          const unsigned short* __restrict__ ql,
                          const unsigned short* __restrict__ kh,
                          const unsigned short* __restrict__ kl,
                          const float* __restrict__ widx,
                          float* __restrict__ scores) {
  int jb = blockIdx.x, tb = blockIdx.y;
  int t0 = tb * 32, j0 = jb * 64;
  if (j0 > t0 + 31) return;
  __shared__ unsigned short Ksh[64][136];
  __shared__ unsigned short Ksl[64][136];
  __shared__ unsigned short Qsh[32][136];
  __shared__ unsigned short Qsl[32][136];
  int tid = threadIdx.x;
#pragma unroll
  for (int i = 0; i < 4; ++i) {
    int e = i * 256 + tid;
    int r = e >> 4, off = (e & 15) * 8;
    *(uint4*)&Ksh[r][off] = *(const uint4*)&kh[(size_t)(j0 + r) * 128 + off];
    *(uint4*)&Ksl[r][off] = *(const uint4*)&kl[(size_t)(j0 + r) * 128 + off];
  }
  int w = tid >> 6, lane = tid & 63;
  int quad = lane >> 4, l16 = lane & 15;
  int wr = w & 1, wc = w >> 1;
  const float* wrow[4];
#pragma unroll
  for (int r = 0; r < 4; ++r)
    wrow[r] = widx + (size_t)(t0 + 16 * wr + quad * 4 + r) * 32;
  float s0[4] = {0.f, 0.f, 0.f, 0.f};
  float s1[4] = {0.f, 0.f, 0.f, 0.f};
  for (int h = 0; h < 32; ++h) {
    __syncthreads();
#pragma unroll
    for (int i = 0; i < 2; ++i) {
      int e = i * 256 + tid;
      int r = e >> 4, off = (e & 15) * 8;
      size_t base = ((size_t)h * T_ + t0 + r) * 128 + off;
      *(uint4*)&Qsh[r][off] = *(const uint4*)&qh[base];
      *(uint4*)&Qsl[r][off] = *(const uint4*)&ql[base];
    }
    __syncthreads();
    f32x4 l0 = {}, l1 = {};
#pragma unroll
    for (int kk = 0; kk < 4; ++kk) {
      bf16x8 ah = *(const bf16x8*)&Qsh[16 * wr + l16][kk * 32 + quad * 8];
      bf16x8 al = *(const bf16x8*)&Qsl[16 * wr + l16][kk * 32 + quad * 8];
      bf16x8 bh0 = *(const bf16x8*)&Ksh[32 * wc + l16][kk * 32 + quad * 8];
      bf16x8 bl0 = *(const bf16x8*)&Ksl[32 * wc + l16][kk * 32 + quad * 8];
      bf16x8 bh1 = *(const bf16x8*)&Ksh[32 * wc + 16 + l16][kk * 32 + quad * 8];
      bf16x8 bl1 = *(const bf16x8*)&Ksl[32 * wc + 16 + l16][kk * 32 + quad * 8];
      l0 = __builtin_amdgcn_mfma_f32_16x16x32_bf16(ah, bh0, l0, 0, 0, 0);
      l0 = __builtin_amdgcn_mfma_f32_16x16x32_bf16(ah, bl0, l0, 0, 0, 0);
      l0 = __builtin_amdgcn_mfma_f32_16x16x32_bf16(al, bh0, l0, 0, 0, 0);
      l1 = __builtin_amdgcn_mfma_f32_16x16x32_bf16(ah, bh1, l1, 0, 0, 0);
      l1 = __builtin_amdgcn_mfma_f32_16x16x32_bf16(ah, bl1, l1, 0, 0, 0);
      l1 = __builtin_amdgcn_mfma_f32_16x16x32_bf16(al, bh1, l1, 0, 0, 0);
    }
#pragma unroll
    for (int r = 0; r < 4; ++r) {
      float wv = wrow[r][h];
      s0[r] = fmaf(wv, fmaxf(l0[r] * ISCALE_, 0.f), s0[r]);
      s1[r] = fmaf(wv, fmaxf(l1[r] * ISCALE_, 0.f), s1[r]);
    }
  }
#pragma unroll
  for (int r = 0; r < 4; ++r) {
    int row = t0 + 16 * wr + quad * 4 + r;
    scores[(size_t)row * T_ + j0 + 32 * wc + l16] = s0[r];
    scores[(size_t)row * T_ + j0 + 32 * wc + 16 + l16] = s1[r];
  }
}

// ---------------- top-k threshold ----------------
__launch_bounds__(256)
__global__ void k_topk(const float* __restrict__ scores, unsigned int* __restrict__ kth) {
  int t = blockIdx.x;
  int n = t + 1;
  if (n <= TOPK_) {
    if (threadIdx.x == 0) kth[t] = 0u;
    return;
  }
  unsigned int keys[8];
#pragma unroll
  for (int m = 0; m < 8; ++m) {
    int j = threadIdx.x + m * 256;
    keys[m] = (j < n) ? mono(scores[(size_t)t * T_ + j]) : 0u;
  }
  __shared__ int wred[4];
  unsigned int thr = 0u;
  for (int b = 31; b >= 0; --b) {
    unsigned int cand = thr | (1u << b);
    int c = 0;
#pragma unroll
    for (int m = 0; m < 8; ++m) c += (keys[m] >= cand) ? 1 : 0;
    for (int o = 32; o > 0; o >>= 1) c += __shfl_down(c, o, 64);
    if ((threadIdx.x & 63) == 0) wred[threadIdx.x >> 6] = c;
    __syncthreads();
    int total = wred[0] + wred[1] + wred[2] + wred[3];
    if (total >= TOPK_) thr = cand;
    __syncthreads();
  }
  if (threadIdx.x == 0) kth[t] = thr;
}

// ---------------- casts for flash: Qb/Kb (head-major bf16) ----------------
__launch_bounds__(256)
__global__ void k_cast_flash(const float* __restrict__ qbuf, const float* __restrict__ kvb,
                             const float* __restrict__ kper,
                             unsigned short* __restrict__ Qb, unsigned short* __restrict__ Kb) {
  int t = blockIdx.x;
  int tid = threadIdx.x;
#pragma unroll
  for (int i = 0; i < 12; ++i) {
    int e = i * 256 + tid;  // 0..3071
    int h = e / 192, d = e % 192;
    Qb[((size_t)h * T_ + t) * 192 + d] = f2bf(qbuf[(size_t)t * 3072 + e]);
    float kv = (d < 128) ? kvb[(size_t)t * 4096 + h * 256 + d]
                         : kper[(size_t)t * 64 + (d - 128)];
    Kb[((size_t)h * T_ + t) * 192 + d] = f2bf(kv);
  }
}

// ---------------- cast V transposed: Vt[h][d][t] bf16 ----------------
__launch_bounds__(256)
__global__ void k_cast_v(const float* __restrict__ kvb, unsigned short* __restrict__ Vt) {
  __shared__ unsigned short vt[128][137];
  int h = blockIdx.y, t0 = blockIdx.x * 128;
  int tid = threadIdx.x;
#pragma unroll
  for (int i = 0; i < 64; ++i) {
    int e = i * 256 + tid;
    int tl = e >> 7, d = e & 127;
    vt[tl][d] = f2bf(kvb[(size_t)(t0 + tl) * 4096 + h * 256 + 128 + d]);
  }
  __syncthreads();
#pragma unroll
  for (int i = 0; i < 64; ++i) {
    int e = i * 256 + tid;
    int d = e >> 7, tl = e & 127;
    Vt[((size_t)h * 128 + d) * T_ + t0 + tl] = vt[tl][d];
  }
}

// ---------------- MFMA flash attention with top-k mask (flash2 body) ----------------
// k_flash5 = flash2 inner structure verbatim; each block processes the
// complementary tile pair {bx, 63-bx} => constant 65 j-tile iterations/block.
__launch_bounds__(256)
__global__ void k_flash5(const unsigned short* __restrict__ Qb,
                         const unsigned short* __restrict__ Kb,
                         const unsigned short* __restrict__ Vt,
                         const float* __restrict__ scores,
                         const unsigned int* __restrict__ kth,
                         unsigned short* __restrict__ obf) {
  __shared__ unsigned short Qs[32][200];
  __shared__ unsigned short Ks[32][200];
  __shared__ unsigned short VsT[128][40];
  __shared__ float Ss[32][33];
  __shared__ unsigned short Ps[32][40];
  __shared__ float m_s[32], l_s[32], al_s[32];

  int bx = blockIdx.x, h = blockIdx.y;
  int tid = threadIdx.x;
  int w = tid >> 6, lane = tid & 63;
  int quad = lane >> 4, l16 = lane & 15;
  int wr = w & 1, wc = w >> 1;

  int srow = tid >> 3;
  int c8 = tid & 7;

  for (int half = 0; half < 2; ++half) {
    int tile = (half == 0) ? bx : (63 - bx);   // 0..63
    int t0 = tile * 32;
    __syncthreads();  // protect m_s/l_s reinit vs prior half's epilogue reads

    // stage Q once (32 x 192 bf16)
#pragma unroll
    for (int i = 0; i < 3; ++i) {
      int c = i * 256 + tid;
      int row = c / 24, off = (c % 24) * 8;
      *(uint4*)&Qs[row][off] =
          *(const uint4*)&Qb[((size_t)h * T_ + t0 + row) * 192 + off];
    }
    if (tid < 32) { m_s[tid] = -INFINITY; l_s[tid] = 0.f; }

    f32x4 Of[4] = {};
    int ig = t0 + srow;

    int njt = tile + 1;
    for (int jt = 0; jt < njt; ++jt) {
      int j0 = jt * 32;
      __syncthreads();
#pragma unroll
      for (int i = 0; i < 3; ++i) {
        int c = i * 256 + tid;
        int row = c / 24, off = (c % 24) * 8;
        *(uint4*)&Ks[row][off] =
            *(const uint4*)&Kb[((size_t)h * T_ + j0 + row) * 192 + off];
      }
#pragma unroll
      for (int i = 0; i < 2; ++i) {
        int c = i * 256 + tid;
        int d = c >> 2, off = (c & 3) * 8;
        *(uint4*)&VsT[d][off] =
            *(const uint4*)&Vt[((size_t)h * 128 + d) * T_ + j0 + off];
      }
      __syncthreads();

      f32x4 Sacc = {};
#pragma unroll
      for (int kk = 0; kk < 6; ++kk) {
        bf16x8 a = *(const bf16x8*)&Qs[16 * wr + l16][kk * 32 + quad * 8];
        bf16x8 b = *(const bf16x8*)&Ks[16 * wc + l16][kk * 32 + quad * 8];
        Sacc = __builtin_amdgcn_mfma_f32_16x16x32_bf16(a, b, Sacc, 0, 0, 0);
      }
#pragma unroll
      for (int r = 0; r < 4; ++r)
        Ss[16 * wr + quad * 4 + r][16 * wc + l16] = Sacc[r];
      __syncthreads();

      float mold = m_s[srow];
      unsigned int kt = kth[ig];
      float4 s4 = *(const float4*)(scores + (size_t)ig * T_ + j0 + 4 * c8);
      float sv[4] = {s4.x, s4.y, s4.z, s4.w};
      float v[4];
#pragma unroll
      for (int c = 0; c < 4; ++c) {
        int jg = j0 + 4 * c8 + c;
        float sc = Ss[srow][4 * c8 + c];
        bool ok = (jg <= ig) && (mono(sv[c]) >= kt);
        v[c] = ok ? sc * SCALE_ : -INFINITY;
      }
      float tmax = fmaxf(fmaxf(v[0], v[1]), fmaxf(v[2], v[3]));
#pragma unroll
      for (int o = 1; o < 8; o <<= 1) tmax = fmaxf(tmax, __shfl_xor(tmax, o, 8));
      float mn = fmaxf(mold, tmax);
      float alpha = (mold == -INFINITY) ? 0.f : expf(mold - mn);
      float p[4], psum = 0.f;
#pragma unroll
      for (int c = 0; c < 4; ++c) {
        p[c] = (v[c] == -INFINITY) ? 0.f : expf(v[c] - mn);
        psum += p[c];
      }
#pragma unroll
      for (int o = 1; o < 8; o <<= 1) psum += __shfl_xor(psum, o, 8);
      if (c8 == 0) {
        m_s[srow] = mn;
        al_s[srow] = alpha;
        l_s[srow] = alpha * l_s[srow] + psum;
      }
#pragma unroll
      for (int c = 0; c < 4; ++c) Ps[srow][4 * c8 + c] = f2bf(p[c]);
      __syncthreads();

      float arow[4];
#pragma unroll
      for (int r = 0; r < 4; ++r) arow[r] = al_s[16 * wr + quad * 4 + r];
      bf16x8 pa = *(const bf16x8*)&Ps[16 * wr + l16][quad * 8];
#pragma unroll
      for (int i = 0; i < 4; ++i) {
#pragma unroll
        for (int r = 0; r < 4; ++r) Of[i][r] *= arow[r];
        bf16x8 vb = *(const bf16x8*)&VsT[16 * (4 * wc + i) + l16][quad * 8];
        Of[i] = __builtin_amdgcn_mfma_f32_16x16x32_bf16(pa, vb, Of[i], 0, 0, 0);
      }
    }

    // epilogue: normalize and write bf16 O (t, h*128+col)
    float linv[4];
#pragma unroll
    for (int r = 0; r < 4; ++r) linv[r] = 1.f / l_s[16 * wr + quad * 4 + r];
#pragma unroll
    for (int i = 0; i < 4; ++i) {
#pragma unroll
      for (int r = 0; r < 4; ++r) {
        int row = t0 + 16 * wr + quad * 4 + r;
        int col = 16 * (4 * wc + i) + l16;
        obf[(size_t)row * 2048 + h * 128 + col] = f2bf(Of[i][r] * linv[r]);
      }
    }
  }
}

}  // namespace

extern "C" void kernel_launch(void* const* d_in, const int* in_sizes, int n_in,
                              void* d_out, int out_size, void* d_ws, size_t ws_size,
                              hipStream_t stream) {
  (void)in_sizes; (void)n_in; (void)out_size; (void)ws_size;
  const int*   positions = (const int*)d_in[0];
  const float* hidden  = (const float*)d_in[1];
  const float* q_c     = (const float*)d_in[2];
  const float* kv_c    = (const float*)d_in[3];
  const float* k_pe    = (const float*)d_in[4];
  const float* q_ln    = (const float*)d_in[5];
  const float* kv_ln   = (const float*)d_in[6];
  const float* Wq_b    = (const float*)d_in[7];
  const float* Wkv_b   = (const float*)d_in[8];
  const float* Wo      = (const float*)d_in[9];
  const float* Wiq     = (const float*)d_in[10];
  const float* Wik     = (const float*)d_in[11];
  const float* ik_g    = (const float*)d_in[12];
  const float* ik_b    = (const float*)d_in[13];
  const float* Ww      = (const float*)d_in[14];
  float* out = (float*)d_out;

  float* ws = (float*)d_ws;
  size_t off = 0;
  float* cosT = ws + off; off += (size_t)T_ * 32;
  float* sinT = ws + off; off += (size_t)T_ * 32;
  float* qcn  = ws + off; off += (size_t)T_ * QLR_;   // slot reused: qcn_lo (bf16)
  float* kvn  = ws + off; off += (size_t)T_ * KVLR_;  // slot reused: kidx hi/lo (bf16)
  float* qbuf = ws + off; off += (size_t)T_ * H_ * 192;  // early overlay: Wiqt hi/lo
  float* kvb  = ws + off; off += (size_t)T_ * H_ * 256;
  float* qidx = ws + off; off += (size_t)T_ * 4096;   // f32; later overlay: Qb/Kb/obf
  float* kidx = ws + off; off += (size_t)T_ * ID_;    // unused (layout stability)
  float* widx = ws + off; off += (size_t)T_ * IH_;
  float* kper = ws + off; off += (size_t)T_ * 64;
  float* scores = ws + off; off += (size_t)T_ * T_;   // early: Wqt+Wkvt, then hgemm partials
  unsigned int* kth = (unsigned int*)(ws + off); off += T_;
  unsigned short* qcn_bf = (unsigned short*)(ws + off); off += (size_t)T_ * QLR_ / 2;
  unsigned short* kvn_bf = (unsigned short*)(ws + off); off += (size_t)T_ * KVLR_ / 2;
  unsigned short* Wot = (unsigned short*)(ws + off); off += (size_t)HID_ * 2048 / 2;
  unsigned short* Vt  = (unsigned short*)(ws + off); off += (size_t)H_ * 128 * T_ / 2;
  unsigned short* qidx_h = (unsigned short*)(ws + off); off += (size_t)T_ * 4096 / 2;
  unsigned short* qidx_l = (unsigned short*)(ws + off); off += (size_t)T_ * 4096 / 2;
  // combined [Wik|Ww]^T bf16 hi/lo (160 x 7168)
  unsigned short* Bikw_h = (unsigned short*)(ws + off); off += (size_t)NC_ * HID_ / 2;
  unsigned short* Bikw_l = (unsigned short*)(ws + off); off += (size_t)NC_ * HID_ / 2;
  (void)kidx;

  // overlays
  unsigned short* Wqt  = (unsigned short*)scores;                  // 3072x1536 bf16
  unsigned short* Wkvt = Wqt + (size_t)3072 * 1536;                // 4096x512 bf16
  float* hpart = scores;                                           // [KSPLIT][T][160] f32
  unsigned short* Qb   = (unsigned short*)qidx;                    // (16,2048,192)
  unsigned short* Kb   = Qb + (size_t)H_ * T_ * 192;               // (16,2048,192)
  unsigned short* obf  = Kb + (size_t)H_ * T_ * 192;               // (2048,2048)
  unsigned short* qcn_lo = (unsigned short*)qcn;                   // T x 1536 bf16
  unsigned short* kidx_h = (unsigned short*)kvn;                   // T x 128 bf16
  unsigned short* kidx_l = kidx_h + (size_t)T_ * ID_;
  unsigned short* Wiqt_h = (unsigned short*)qbuf;                  // 4096x1536 bf16 (dead before Wq GEMM)
  unsigned short* Wiqt_l = Wiqt_h + (size_t)4096 * QLR_;

  k_tables<<<dim3(T_ * 32 / 256), dim3(256), 0, stream>>>(positions, cosT, sinT);
  k_rms<QLR_><<<dim3(T_), dim3(256), 0, stream>>>(q_c, q_ln, qcn_bf, qcn_lo);
  k_rms<KVLR_><<<dim3(T_), dim3(256), 0, stream>>>(kv_c, kv_ln, kvn_bf, nullptr);
  // indexer qidx GEMM first (Wiqt overlays qbuf, which the Wq GEMM overwrites later)
  k_tc2<<<dim3(4096 / 64, QLR_ / 64), dim3(256), 0, stream>>>(Wiq, Wiqt_h, Wiqt_l, QLR_, 4096);
  k_gemm3<<<dim3(4096 / 128, T_ / 128), dim3(256), 0, stream>>>(qcn_bf, qcn_lo, Wiqt_h, Wiqt_l,
                                                                qidx, T_, 4096, QLR_);
  k_qidx_prep<<<dim3(T_), dim3(256), 0, stream>>>(qidx, cosT, sinT, qidx_h, qidx_l);
  // attention-path weight casts + GEMMs (consume Wqt/Wkvt before hgemm partials overwrite)
  k_tc<<<dim3(3072 / 64, QLR_ / 64), dim3(256), 0, stream>>>(Wq_b, Wqt, QLR_, 3072);
  k_tc<<<dim3(4096 / 64, KVLR_ / 64), dim3(256), 0, stream>>>(Wkv_b, Wkvt, KVLR_, 4096);
  k_tc<<<dim3(HID_ / 64, 2048 / 64), dim3(256), 0, stream>>>(Wo, Wot, 2048, HID_);
  k_tc2w<<<dim3(HID_ / 64, 3), dim3(256), 0, stream>>>(Wik, Ww, Bikw_h, Bikw_l);
  k_gemm_bf<<<dim3(3072 / 128, T_ / 128), dim3(256), 0, stream>>>(qcn_bf, Wqt, qbuf, T_, 3072, QLR_);
  k_rope_q<<<dim3(T_ * H_ * 32 / 256), dim3(256), 0, stream>>>(qbuf, cosT, sinT);
  k_gemm_bf<<<dim3(4096 / 128, T_ / 128), dim3(256), 0, stream>>>(kvn_bf, Wkvt, kvb, T_, 4096, KVLR_);
  // fused hidden GEMM (partials into scores region; Wqt/Wkvt now dead)
  k_hgemm<<<dim3(KSPLIT_, T_ / 64), dim3(256), 0, stream>>>(hidden, Bikw_h, Bikw_l, hpart);
  k_kidx_fin<<<dim3(T_), dim3(192), 0, stream>>>(hpart, ik_g, ik_b, cosT, sinT,
                                                 kidx_h, kidx_l, widx);
  k_rope_kpe<<<dim3(T_ * 32 / 256), dim3(256), 0, stream>>>(k_pe, cosT, sinT, kper);
  // scores AFTER fin (scores region overwrites hgemm partials)
  k_scores3<<<dim3(T_ / 64, T_ / 32), dim3(256), 0, stream>>>(qidx_h, qidx_l, kidx_h, kidx_l,
                                                              widx, scores);
  k_topk<<<dim3(T_), dim3(256), 0, stream>>>(scores, kth);
  // casts AFTER k_qidx_prep (Qb/Kb/obf overlay the dead f32 qidx)
  k_cast_flash<<<dim3(T_), dim3(256), 0, stream>>>(qbuf, kvb, kper, Qb, Kb);
  k_cast_v<<<dim3(T_ / 128, H_), dim3(256), 0, stream>>>(kvb, Vt);
  k_flash5<<<dim3(32, H_), dim3(256), 0, stream>>>(Qb, Kb, Vt, scores, kth, obf);
  k_gemm_bf<<<dim3(HID_ / 128, T_ / 128), dim3(256), 0, stream>>>(obf, Wot, out, T_, HID_, 2048);
}

// Round 13
// 853.312 us; speedup vs baseline: 1.4595x; 1.0194x over previous
//
#include <hip/hip_runtime.h>
#include <hip/hip_bf16.h>
#include <math.h>

// DeepseekV32 MLA attention + lightning indexer, MI355X (gfx950).
// Round 15: k_flash5 shows 276MB FETCH (~13x over unique K/V: each head's
// 1.3MB L2-resident working set is re-fetched by every XCD because the 2D
// grid round-robins a head's blocks across all 8 XCD L2s). Flatten to 1D
// grid + XCD-aware swizzle: all 32 blocks of a head land on one XCD
// (2 heads/XCD = 2.6MB <= 4MB L2). Kernel body unchanged.

namespace {

constexpr int T_    = 2048;
constexpr int HID_  = 7168;
constexpr int H_    = 16;
constexpr int QLR_  = 1536;
constexpr int KVLR_ = 512;
constexpr int IH_   = 32;
constexpr int ID_   = 128;
constexpr int TOPK_ = 512;
constexpr float EPS_    = 1e-6f;
constexpr float SCALE_  = 0.07216878364870322f;   // (128+64)^-0.5
constexpr float ISCALE_ = 0.08838834764831845f;   // 128^-0.5
constexpr float WSCALE_ = 0.17677669529663687f;   // 32^-0.5

// hidden GEMM: split-K config
constexpr int KSPLIT_ = 8;
constexpr int KC_     = HID_ / KSPLIT_;  // 896 = 28 steps of 32
constexpr int NC_     = 160;             // 128 (Wik) + 32 (Ww)

typedef __attribute__((ext_vector_type(8))) short bf16x8;
typedef __attribute__((ext_vector_type(4))) float f32x4;

__device__ __forceinline__ unsigned int mono(float x) {
  unsigned int u = __float_as_uint(x);
  return (u & 0x80000000u) ? ~u : (u | 0x80000000u);
}

__device__ __forceinline__ unsigned short f2bf(float x) {
  unsigned int u = __float_as_uint(x);
  u += 0x7FFFu + ((u >> 16) & 1u);
  return (unsigned short)(u >> 16);
}

__device__ __forceinline__ float bf2f(unsigned short h) {
  return __uint_as_float((unsigned int)h << 16);
}

// ---------------- rope tables ----------------
__global__ void k_tables(const int* __restrict__ pos, float* __restrict__ cosT,
                         float* __restrict__ sinT) {
  int idx = blockIdx.x * 256 + threadIdx.x;
  if (idx >= T_ * 32) return;
  int t = idx >> 5, i = idx & 31;
  float invf = (float)pow(10000.0, -(double)i / 32.0);
  float ang = (float)pos[t] * invf;
  cosT[idx] = cosf(ang);
  sinT[idx] = sinf(ang);
}

// ---------------- rmsnorm: bf16 hi (+ optional lo residual) ----------------
template <int N>
__launch_bounds__(256)
__global__ void k_rms(const float* __restrict__ x, const float* __restrict__ w,
                      unsigned short* __restrict__ yhi, unsigned short* __restrict__ ylo) {
  int t = blockIdx.x;
  const float* xr = x + (size_t)t * N;
  float ss = 0.f;
  for (int c = threadIdx.x; c < N; c += 256) { float v = xr[c]; ss += v * v; }
  __shared__ float red[256];
  red[threadIdx.x] = ss;
  __syncthreads();
  for (int off = 128; off > 0; off >>= 1) {
    if (threadIdx.x < off) red[threadIdx.x] += red[threadIdx.x + off];
    __syncthreads();
  }
  float sc = rsqrtf(red[0] * (1.f / N) + EPS_);
  unsigned short* yhr = yhi + (size_t)t * N;
  unsigned short* ylr = ylo ? ylo + (size_t)t * N : nullptr;
  for (int c = threadIdx.x; c < N; c += 256) {
    float v = xr[c] * sc * w[c];
    unsigned short hb = f2bf(v);
    yhr[c] = hb;
    if (ylr) ylr[c] = f2bf(v - bf2f(hb));
  }
}

// ---------------- transpose-cast: W (K x N, f32) -> Wt (N x K, bf16) ----------------
__launch_bounds__(256)
__global__ void k_tc(const float* __restrict__ W, unsigned short* __restrict__ Wt,
                     int K, int N) {
  __shared__ float tile[64][65];
  int k0 = blockIdx.y * 64, n0 = blockIdx.x * 64;
  int tid = threadIdx.x;
#pragma unroll
  for (int i = 0; i < 16; ++i) {
    int e = i * 256 + tid;
    int r = e >> 6, c = e & 63;
    tile[r][c] = W[(size_t)(k0 + r) * N + n0 + c];
  }
  __syncthreads();
#pragma unroll
  for (int i = 0; i < 16; ++i) {
    int e = i * 256 + tid;
    int r = e >> 6, c = e & 63;
    Wt[(size_t)(n0 + r) * K + k0 + c] = f2bf(tile[c][r]);
  }
}

// ---------------- transpose + split-cast: W (K x N, f32) -> Wt_hi/Wt_lo (N x K) ----------------
__launch_bounds__(256)
__global__ void k_tc2(const float* __restrict__ W, unsigned short* __restrict__ Wth,
                      unsigned short* __restrict__ Wtl, int K, int N) {
  __shared__ float tile[64][65];
  int k0 = blockIdx.y * 64, n0 = blockIdx.x * 64;
  int tid = threadIdx.x;
#pragma unroll
  for (int i = 0; i < 16; ++i) {
    int e = i * 256 + tid;
    int r = e >> 6, c = e & 63;
    tile[r][c] = W[(size_t)(k0 + r) * N + n0 + c];
  }
  __syncthreads();
#pragma unroll
  for (int i = 0; i < 16; ++i) {
    int e = i * 256 + tid;
    int r = e >> 6, c = e & 63;
    float v = tile[c][r];
    unsigned short hb = f2bf(v);
    size_t o = (size_t)(n0 + r) * K + k0 + c;
    Wth[o] = hb;
    Wtl[o] = f2bf(v - bf2f(hb));
  }
}

// ---------------- combined [Wik | Ww] transpose + split-cast -> (160 x 7168) hi/lo ----------------
__launch_bounds__(256)
__global__ void k_tc2w(const float* __restrict__ Wik, const float* __restrict__ Ww,
                       unsigned short* __restrict__ Bth, unsigned short* __restrict__ Btl) {
  __shared__ float tile[64][65];
  int k0 = blockIdx.x * 64;
  int ny = blockIdx.y;              // 0,1: Wik cols; 2: Ww cols (32)
  int ncols = (ny == 2) ? 32 : 64;
  int tid = threadIdx.x;
#pragma unroll
  for (int i = 0; i < 16; ++i) {
    int e = i * 256 + tid;
    int r = e >> 6, c = e & 63;
    if (c < ncols)
      tile[r][c] = (ny == 2) ? Ww[(size_t)(k0 + r) * 32 + c]
                             : Wik[(size_t)(k0 + r) * 128 + ny * 64 + c];
  }
  __syncthreads();
#pragma unroll
  for (int i = 0; i < 16; ++i) {
    int e = i * 256 + tid;
    int r = e >> 6, c = e & 63;
    if (r < ncols) {
      float v = tile[c][r];
      unsigned short hb = f2bf(v);
      size_t o = (size_t)(ny * 64 + r) * HID_ + k0 + c;
      Bth[o] = hb;
      Btl[o] = f2bf(v - bf2f(hb));
    }
  }
}

// ---------------- bf16 MFMA GEMM: C(M,N) f32 = A(M,K) bf16 @ Bt(N,K) bf16 ----------------
__launch_bounds__(256)
__global__ void k_gemm_bf(const unsigned short* __restrict__ A,
                          const unsigned short* __restrict__ Bt,
                          float* __restrict__ C, int M, int N, int K) {
  __shared__ unsigned short As[128][40];
  __shared__ unsigned short Bs[128][40];
  int m0 = blockIdx.y * 128, n0 = blockIdx.x * 128;
  int tid = threadIdx.x;
  int w = tid >> 6, lane = tid & 63;
  int quad = lane >> 4, l16 = lane & 15;
  int wr = w & 1, wc = w >> 1;
  f32x4 acc[4][4] = {};
  for (int k0 = 0; k0 < K; k0 += 32) {
    __syncthreads();
#pragma unroll
    for (int i = 0; i < 2; ++i) {
      int c = i * 256 + tid;
      int row = c >> 2, off = (c & 3) * 8;
      *(uint4*)&As[row][off] = *(const uint4*)&A[(size_t)(m0 + row) * K + k0 + off];
      *(uint4*)&Bs[row][off] = *(const uint4*)&Bt[(size_t)(n0 + row) * K + k0 + off];
    }
    __syncthreads();
    bf16x8 a[4], b[4];
#pragma unroll
    for (int mi = 0; mi < 4; ++mi) a[mi] = *(const bf16x8*)&As[64 * wr + 16 * mi + l16][quad * 8];
#pragma unroll
    for (int ni = 0; ni < 4; ++ni) b[ni] = *(const bf16x8*)&Bs[64 * wc + 16 * ni + l16][quad * 8];
#pragma unroll
    for (int mi = 0; mi < 4; ++mi)
#pragma unroll
      for (int ni = 0; ni < 4; ++ni)
        acc[mi][ni] = __builtin_amdgcn_mfma_f32_16x16x32_bf16(a[mi], b[ni], acc[mi][ni], 0, 0, 0);
  }
#pragma unroll
  for (int mi = 0; mi < 4; ++mi)
#pragma unroll
    for (int ni = 0; ni < 4; ++ni)
#pragma unroll
      for (int r = 0; r < 4; ++r) {
        int row = m0 + 64 * wr + 16 * mi + quad * 4 + r;
        int col = n0 + 64 * wc + 16 * ni + l16;
        C[(size_t)row * N + col] = acc[mi][ni][r];
      }
}

// ---------------- split-bf16 3-pass GEMM: C f32 = (Ah+Al)(M,K) @ (Bh+Bl)t(N,K) ----------------
__launch_bounds__(256)
__global__ void k_gemm3(const unsigned short* __restrict__ Ah,
                        const unsigned short* __restrict__ Al,
                        const unsigned short* __restrict__ Bth,
                        const unsigned short* __restrict__ Btl,
                        float* __restrict__ C, int M, int N, int K) {
  __shared__ unsigned short Ash[128][40];
  __shared__ unsigned short Asl[128][40];
  __shared__ unsigned short Bsh[128][40];
  __shared__ unsigned short Bsl[128][40];
  int m0 = blockIdx.y * 128, n0 = blockIdx.x * 128;
  int tid = threadIdx.x;
  int w = tid >> 6, lane = tid & 63;
  int quad = lane >> 4, l16 = lane & 15;
  int wr = w & 1, wc = w >> 1;
  f32x4 acc[4][4] = {};
  for (int k0 = 0; k0 < K; k0 += 32) {
    __syncthreads();
#pragma unroll
    for (int i = 0; i < 2; ++i) {
      int c = i * 256 + tid;
      int row = c >> 2, off = (c & 3) * 8;
      *(uint4*)&Ash[row][off] = *(const uint4*)&Ah[(size_t)(m0 + row) * K + k0 + off];
      *(uint4*)&Asl[row][off] = *(const uint4*)&Al[(size_t)(m0 + row) * K + k0 + off];
      *(uint4*)&Bsh[row][off] = *(const uint4*)&Bth[(size_t)(n0 + row) * K + k0 + off];
      *(uint4*)&Bsl[row][off] = *(const uint4*)&Btl[(size_t)(n0 + row) * K + k0 + off];
    }
    __syncthreads();
    bf16x8 ah[4], al[4];
#pragma unroll
    for (int mi = 0; mi < 4; ++mi) {
      ah[mi] = *(const bf16x8*)&Ash[64 * wr + 16 * mi + l16][quad * 8];
      al[mi] = *(const bf16x8*)&Asl[64 * wr + 16 * mi + l16][quad * 8];
    }
#pragma unroll
    for (int nh = 0; nh < 2; ++nh) {
      bf16x8 bh[2], bl[2];
#pragma unroll
      for (int nj = 0; nj < 2; ++nj) {
        int nrow = 64 * wc + 16 * (2 * nh + nj) + l16;
        bh[nj] = *(const bf16x8*)&Bsh[nrow][quad * 8];
        bl[nj] = *(const bf16x8*)&Bsl[nrow][quad * 8];
      }
#pragma unroll
      for (int mi = 0; mi < 4; ++mi)
#pragma unroll
        for (int nj = 0; nj < 2; ++nj) {
          int ni = 2 * nh + nj;
          acc[mi][ni] = __builtin_amdgcn_mfma_f32_16x16x32_bf16(ah[mi], bh[nj], acc[mi][ni], 0, 0, 0);
          acc[mi][ni] = __builtin_amdgcn_mfma_f32_16x16x32_bf16(ah[mi], bl[nj], acc[mi][ni], 0, 0, 0);
          acc[mi][ni] = __builtin_amdgcn_mfma_f32_16x16x32_bf16(al[mi], bh[nj], acc[mi][ni], 0, 0, 0);
        }
    }
  }
#pragma unroll
  for (int mi = 0; mi < 4; ++mi)
#pragma unroll
    for (int ni = 0; ni < 4; ++ni)
#pragma unroll
      for (int r = 0; r < 4; ++r) {
        int row = m0 + 64 * wr + 16 * mi + quad * 4 + r;
        int col = n0 + 64 * wc + 16 * ni + l16;
        C[(size_t)row * N + col] = acc[mi][ni][r];
      }
}

// ---------------- fused hidden GEMM: part[s] = hidden(64-tile, Kc) @ [Wik|Ww]^T ----------------
__launch_bounds__(256)
__global__ void k_hgemm(const float* __restrict__ hidden,
                        const unsigned short* __restrict__ Bth,
                        const unsigned short* __restrict__ Btl,
                        float* __restrict__ part) {
  __shared__ unsigned short Ash[64][40];
  __shared__ unsigned short Asl[64][40];
  __shared__ unsigned short Bsh[NC_][40];
  __shared__ unsigned short Bsl[NC_][40];
  int ks = blockIdx.x, m0 = blockIdx.y * 64;
  int kc0 = ks * KC_;
  int tid = threadIdx.x;
  int w = tid >> 6, lane = tid & 63;
  int quad = lane >> 4, l16 = lane & 15;
  int wr = w & 1, wc = w >> 1;   // wave: 32 rows x 80 cols
  f32x4 acc[2][5] = {};
  for (int s = 0; s < KC_ / 32; ++s) {
    int k0 = kc0 + s * 32;
    __syncthreads();
#pragma unroll
    for (int i = 0; i < 2; ++i) {
      int c = i * 256 + tid;          // 0..511
      int row = c >> 3, off = (c & 7) * 4;
      float4 v = *(const float4*)&hidden[(size_t)(m0 + row) * HID_ + k0 + off];
      ushort4 hv, lv;
      hv.x = f2bf(v.x); lv.x = f2bf(v.x - bf2f(hv.x));
      hv.y = f2bf(v.y); lv.y = f2bf(v.y - bf2f(hv.y));
      hv.z = f2bf(v.z); lv.z = f2bf(v.z - bf2f(hv.z));
      hv.w = f2bf(v.w); lv.w = f2bf(v.w - bf2f(hv.w));
      *(ushort4*)&Ash[row][off] = hv;
      *(ushort4*)&Asl[row][off] = lv;
    }
#pragma unroll
    for (int i = 0; i < 3; ++i) {
      int c = i * 256 + tid;          // 0..639 valid
      if (c < NC_ * 4) {
        int row = c >> 2, off = (c & 3) * 8;
        *(uint4*)&Bsh[row][off] = *(const uint4*)&Bth[(size_t)row * HID_ + k0 + off];
        *(uint4*)&Bsl[row][off] = *(const uint4*)&Btl[(size_t)row * HID_ + k0 + off];
      }
    }
    __syncthreads();
    bf16x8 ah[2], al[2];
#pragma unroll
    for (int mi = 0; mi < 2; ++mi) {
      ah[mi] = *(const bf16x8*)&Ash[32 * wr + 16 * mi + l16][quad * 8];
      al[mi] = *(const bf16x8*)&Asl[32 * wr + 16 * mi + l16][quad * 8];
    }
#pragma unroll
    for (int ni = 0; ni < 5; ++ni) {
      int nrow = 80 * wc + 16 * ni + l16;
      bf16x8 bh = *(const bf16x8*)&Bsh[nrow][quad * 8];
      bf16x8 bl = *(const bf16x8*)&Bsl[nrow][quad * 8];
#pragma unroll
      for (int mi = 0; mi < 2; ++mi) {
        acc[mi][ni] = __builtin_amdgcn_mfma_f32_16x16x32_bf16(ah[mi], bh, acc[mi][ni], 0, 0, 0);
        acc[mi][ni] = __builtin_amdgcn_mfma_f32_16x16x32_bf16(ah[mi], bl, acc[mi][ni], 0, 0, 0);
        acc[mi][ni] = __builtin_amdgcn_mfma_f32_16x16x32_bf16(al[mi], bh, acc[mi][ni], 0, 0, 0);
      }
    }
  }
#pragma unroll
  for (int mi = 0; mi < 2; ++mi)
#pragma unroll
    for (int ni = 0; ni < 5; ++ni)
#pragma unroll
      for (int r = 0; r < 4; ++r) {
        int row = m0 + 32 * wr + 16 * mi + quad * 4 + r;
        int col = 80 * wc + 16 * ni + l16;
        part[((size_t)ks * T_ + row) * NC_ + col] = acc[mi][ni][r];
      }
}

// ---------------- reduce partials + LN + rope -> kidx hi/lo; cols 128..159 -> widx ----------------
__launch_bounds__(192)
__global__ void k_kidx_fin(const float* __restrict__ part,
                           const float* __restrict__ gamma, const float* __restrict__ beta,
                           const float* __restrict__ cosT, const float* __restrict__ sinT,
                           unsigned short* __restrict__ kh, unsigned short* __restrict__ kl,
                           float* __restrict__ widx) {
  int t = blockIdx.x;
  int tid = threadIdx.x;
  float y = 0.f;
  if (tid < NC_) {
#pragma unroll
    for (int s = 0; s < KSPLIT_; ++s) y += part[((size_t)s * T_ + t) * NC_ + tid];
  }
  __shared__ float red[128];
  __shared__ float sm2[2];
  __shared__ float yn[128];
  if (tid < 128) red[tid] = y;
  __syncthreads();
  for (int off = 64; off > 0; off >>= 1) {
    if (tid < off) red[tid] += red[tid + off];
    __syncthreads();
  }
  if (tid == 0) sm2[0] = red[0] * (1.f / 128.f);
  __syncthreads();
  float mu = sm2[0];
  if (tid < 128) { float d = y - mu; red[tid] = d * d; }
  __syncthreads();
  for (int off = 64; off > 0; off >>= 1) {
    if (tid < off) red[tid] += red[tid + off];
    __syncthreads();
  }
  if (tid == 0) sm2[1] = red[0] * (1.f / 128.f);
  __syncthreads();
  if (tid < 128) {
    float rstd = rsqrtf(sm2[1] + EPS_);
    yn[tid] = (y - mu) * rstd * gamma[tid] + beta[tid];
  }
  __syncthreads();
  if (tid < 32) {
    int i = tid;
    float co = cosT[t * 32 + i], si = sinT[t * 32 + i];
    float a = yn[i], b = yn[i + 32];
    float v0 = a * co - b * si;
    float v1 = b * co + a * si;
    unsigned short h0 = f2bf(v0);
    kh[(size_t)t * ID_ + i] = h0;
    kl[(size_t)t * ID_ + i] = f2bf(v0 - bf2f(h0));
    unsigned short h1 = f2bf(v1);
    kh[(size_t)t * ID_ + i + 32] = h1;
    kl[(size_t)t * ID_ + i + 32] = f2bf(v1 - bf2f(h1));
  } else if (tid >= 64 && tid < 128) {
    float v = yn[tid];
    unsigned short hb = f2bf(v);
    kh[(size_t)t * ID_ + tid] = hb;
    kl[(size_t)t * ID_ + tid] = f2bf(v - bf2f(hb));
  } else if (tid >= 128 && tid < 160) {
    widx[(size_t)t * 32 + (tid - 128)] = y * WSCALE_;
  }
}

// ---------------- rope kernels ----------------
__global__ void k_rope_q(float* __restrict__ q, const float* __restrict__ cosT,
                         const float* __restrict__ sinT) {
  int idx = blockIdx.x * 256 + threadIdx.x;
  if (idx >= T_ * H_ * 32) return;
  int i = idx & 31;
  int th = idx >> 5;
  int h = th & 15, t = th >> 4;
  float c = cosT[t * 32 + i], s = sinT[t * 32 + i];
  float* p = q + (size_t)t * 3072 + h * 192 + 128 + 2 * i;
  float e = p[0], o = p[1];
  p[0] = e * c - o * s;
  p[1] = o * c + e * s;
}

// fused neox-rope + split-cast to head-major (IH, T, ID) bf16 hi/lo
__launch_bounds__(256)
__global__ void k_qidx_prep(const float* __restrict__ qidx,
                            const float* __restrict__ cosT, const float* __restrict__ sinT,
                            unsigned short* __restrict__ qh, unsigned short* __restrict__ ql) {
  int t = blockIdx.x;
  int tid = threadIdx.x;
#pragma unroll
  for (int m = 0; m < 4; ++m) {
    int e = m * 256 + tid;          // 0..1023
    int h = e >> 5, i = e & 31;
    float c = cosT[t * 32 + i], s = sinT[t * 32 + i];
    const float* p = qidx + (size_t)t * 4096 + h * 128;
    float a = p[i], b = p[i + 32];
    float o0 = a * c - b * s;
    float o1 = b * c + a * s;
    size_t base = ((size_t)h * T_ + t) * 128;
    unsigned short h0 = f2bf(o0);
    qh[base + i] = h0;
    ql[base + i] = f2bf(o0 - bf2f(h0));
    unsigned short h1 = f2bf(o1);
    qh[base + i + 32] = h1;
    ql[base + i + 32] = f2bf(o1 - bf2f(h1));
  }
#pragma unroll
  for (int m = 0; m < 8; ++m) {
    int e = m * 256 + tid;          // 0..2047
    int h = e >> 6, d = 64 + (e & 63);
    float v = qidx[(size_t)t * 4096 + h * 128 + d];
    size_t o = ((size_t)h * T_ + t) * 128 + d;
    unsigned short hb = f2bf(v);
    qh[o] = hb;
    ql[o] = f2bf(v - bf2f(hb));
  }
}

__global__ void k_rope_kpe(const float* __restrict__ kpe, const float* __restrict__ cosT,
                           const float* __restrict__ sinT, float* __restrict__ kper) {
  int idx = blockIdx.x * 256 + threadIdx.x;
  if (idx >= T_ * 32) return;
  int i = idx & 31, t = idx >> 5;
  float c = cosT[idx], s = sinT[idx];
  float e = kpe[(size_t)t * 64 + 2 * i], o = kpe[(size_t)t * 64 + 2 * i + 1];
  kper[(size_t)t * 64 + 2 * i] = e * c - o * s;
  kper[(size_t)t * 64 + 2 * i + 1] = o * c + e * s;
}

// ---------------- indexer scores via split-bf16 3-pass MFMA (round-10 body, no Wsh) ----------------
__launch_bounds__(256)
__global__ void k_scores3(const unsigned short* __restrict__ qh,
                          const unsigned short* __restrict__ ql,
                          const unsigned short* __restrict__ kh,
                          const unsigned short* __restrict__ kl,
                          const float* __restrict__ widx,
                          float* __restrict__ scores) {
  int jb = blockIdx.x, tb = blockIdx.y;
  int t0 = tb * 32, j0 = jb * 64;
  if (j0 > t0 + 31) return;
  __shared__ unsigned short Ksh[64][136];
  __shared__ unsigned short Ksl[64][136];
  __shared__ unsigned short Qsh[32][136];
  __shared__ unsigned short Qsl[32][136];
  int tid = threadIdx.x;
#pragma unroll
  for (int i = 0; i < 4; ++i) {
    int e = i * 256 + tid;
    int r = e >> 4, off = (e & 15) * 8;
    *(uint4*)&Ksh[r][off] = *(const uint4*)&kh[(size_t)(j0 + r) * 128 + off];
    *(uint4*)&Ksl[r][off] = *(const uint4*)&kl[(size_t)(j0 + r) * 128 + off];
  }
  int w = tid >> 6, lane = tid & 63;
  int quad = lane >> 4, l16 = lane & 15;
  int wr = w & 1, wc = w >> 1;
  const float* wrow[4];
#pragma unroll
  for (int r = 0; r < 4; ++r)
    wrow[r] = widx + (size_t)(t0 + 16 * wr + quad * 4 + r) * 32;
  float s0[4] = {0.f, 0.f, 0.f, 0.f};
  float s1[4] = {0.f, 0.f, 0.f, 0.f};
  for (int h = 0; h < 32; ++h) {
    __syncthreads();
#pragma unroll
    for (int i = 0; i < 2; ++i) {
      int e = i * 256 + tid;
      int r = e >> 4, off = (e & 15) * 8;
      size_t base = ((size_t)h * T_ + t0 + r) * 128 + off;
      *(uint4*)&Qsh[r][off] = *(const uint4*)&qh[base];
      *(uint4*)&Qsl[r][off] = *(const uint4*)&ql[base];
    }
    __syncthreads();
    f32x4 l0 = {}, l1 = {};
#pragma unroll
    for (int kk = 0; kk < 4; ++kk) {
      bf16x8 ah = *(const bf16x8*)&Qsh[16 * wr + l16][kk * 32 + quad * 8];
      bf16x8 al = *(const bf16x8*)&Qsl[16 * wr + l16][kk * 32 + quad * 8];
      bf16x8 bh0 = *(const bf16x8*)&Ksh[32 * wc + l16][kk * 32 + quad * 8];
      bf16x8 bl0 = *(const bf16x8*)&Ksl[32 * wc + l16][kk * 32 + quad * 8];
      bf16x8 bh1 = *(const bf16x8*)&Ksh[32 * wc + 16 + l16][kk * 32 + quad * 8];
      bf16x8 bl1 = *(const bf16x8*)&Ksl[32 * wc + 16 + l16][kk * 32 + quad * 8];
      l0 = __builtin_amdgcn_mfma_f32_16x16x32_bf16(ah, bh0, l0, 0, 0, 0);
      l0 = __builtin_amdgcn_mfma_f32_16x16x32_bf16(ah, bl0, l0, 0, 0, 0);
      l0 = __builtin_amdgcn_mfma_f32_16x16x32_bf16(al, bh0, l0, 0, 0, 0);
      l1 = __builtin_amdgcn_mfma_f32_16x16x32_bf16(ah, bh1, l1, 0, 0, 0);
      l1 = __builtin_amdgcn_mfma_f32_16x16x32_bf16(ah, bl1, l1, 0, 0, 0);
      l1 = __builtin_amdgcn_mfma_f32_16x16x32_bf16(al, bh1, l1, 0, 0, 0);
    }
#pragma unroll
    for (int r = 0; r < 4; ++r) {
      float wv = wrow[r][h];
      s0[r] = fmaf(wv, fmaxf(l0[r] * ISCALE_, 0.f), s0[r]);
      s1[r] = fmaf(wv, fmaxf(l1[r] * ISCALE_, 0.f), s1[r]);
    }
  }
#pragma unroll
  for (int r = 0; r < 4; ++r) {
    int row = t0 + 16 * wr + quad * 4 + r;
    scores[(size_t)row * T_ + j0 + 32 * wc + l16] = s0[r];
    scores[(size_t)row * T_ + j0 + 32 * wc + 16 + l16] = s1[r];
  }
}

// ---------------- top-k threshold ----------------
__launch_bounds__(256)
__global__ void k_topk(const float* __restrict__ scores, unsigned int* __restrict__ kth) {
  int t = blockIdx.x;
  int n = t + 1;
  if (n <= TOPK_) {
    if (threadIdx.x == 0) kth[t] = 0u;
    return;
  }
  unsigned int keys[8];
#pragma unroll
  for (int m = 0; m < 8; ++m) {
    int j = threadIdx.x + m * 256;
    keys[m] = (j < n) ? mono(scores[(size_t)t * T_ + j]) : 0u;
  }
  __shared__ int wred[4];
  unsigned int thr = 0u;
  for (int b = 31; b >= 0; --b) {
    unsigned int cand = thr | (1u << b);
    int c = 0;
#pragma unroll
    for (int m = 0; m < 8; ++m) c += (keys[m] >= cand) ? 1 : 0;
    for (int o = 32; o > 0; o >>= 1) c += __shfl_down(c, o, 64);
    if ((threadIdx.x & 63) == 0) wred[threadIdx.x >> 6] = c;
    __syncthreads();
    int total = wred[0] + wred[1] + wred[2] + wred[3];
    if (total >= TOPK_) thr = cand;
    __syncthreads();
  }
  if (threadIdx.x == 0) kth[t] = thr;
}

// ---------------- casts for flash: Qb/Kb (head-major bf16) ----------------
__launch_bounds__(256)
__global__ void k_cast_flash(const float* __restrict__ qbuf, const float* __restrict__ kvb,
                             const float* __restrict__ kper,
                             unsigned short* __restrict__ Qb, unsigned short* __restrict__ Kb) {
  int t = blockIdx.x;
  int tid = threadIdx.x;
#pragma unroll
  for (int i = 0; i < 12; ++i) {
    int e = i * 256 + tid;  // 0..3071
    int h = e / 192, d = e % 192;
    Qb[((size_t)h * T_ + t) * 192 + d] = f2bf(qbuf[(size_t)t * 3072 + e]);
    float kv = (d < 128) ? kvb[(size_t)t * 4096 + h * 256 + d]
                         : kper[(size_t)t * 64 + (d - 128)];
    Kb[((size_t)h * T_ + t) * 192 + d] = f2bf(kv);
  }
}

// ---------------- cast V transposed: Vt[h][d][t] bf16 ----------------
__launch_bounds__(256)
__global__ void k_cast_v(const float* __restrict__ kvb, unsigned short* __restrict__ Vt) {
  __shared__ unsigned short vt[128][137];
  int h = blockIdx.y, t0 = blockIdx.x * 128;
  int tid = threadIdx.x;
#pragma unroll
  for (int i = 0; i < 64; ++i) {
    int e = i * 256 + tid;
    int tl = e >> 7, d = e & 127;
    vt[tl][d] = f2bf(kvb[(size_t)(t0 + tl) * 4096 + h * 256 + 128 + d]);
  }
  __syncthreads();
#pragma unroll
  for (int i = 0; i < 64; ++i) {
    int e = i * 256 + tid;
    int d = e >> 7, tl = e & 127;
    Vt[((size_t)h * 128 + d) * T_ + t0 + tl] = vt[tl][d];
  }
}

// ---------------- MFMA flash attention with top-k mask (flash2 body) ----------------
// k_flash5: flash2 inner structure verbatim; complementary tile pair
// {bx, 63-bx} per block (65 j-tiles each). 1D grid of 512 with XCD-aware
// swizzle: all 32 blocks of a head land on one XCD (wgid%8 = h/2), so the
// head's 1.3MB K/V set stays in that XCD's L2 (2 heads x 1.3MB <= 4MB).
__launch_bounds__(256)
__global__ void k_flash5(const unsigned short* __restrict__ Qb,
                         const unsigned short* __restrict__ Kb,
                         const unsigned short* __restrict__ Vt,
                         const float* __restrict__ scores,
                         const unsigned int* __restrict__ kth,
                         unsigned short* __restrict__ obf) {
  __shared__ unsigned short Qs[32][200];
  __shared__ unsigned short Ks[32][200];
  __shared__ unsigned short VsT[128][40];
  __shared__ float Ss[32][33];
  __shared__ unsigned short Ps[32][40];
  __shared__ float m_s[32], l_s[32], al_s[32];

  // XCD-aware decomposition: wgid%8 = XCD (dispatch round-robin heuristic).
  int wgid = blockIdx.x;            // 0..511
  int xcd = wgid & 7;
  int slot = wgid >> 3;             // 0..63
  int h = xcd * 2 + (slot >> 5);    // 2 heads per XCD
  int bx = slot & 31;

  int tid = threadIdx.x;
  int w = tid >> 6, lane = tid & 63;
  int quad = lane >> 4, l16 = lane & 15;
  int wr = w & 1, wc = w >> 1;

  int srow = tid >> 3;
  int c8 = tid & 7;

  for (int half = 0; half < 2; ++half) {
    int tile = (half == 0) ? bx : (63 - bx);   // 0..63
    int t0 = tile * 32;
    __syncthreads();  // protect m_s/l_s reinit vs prior half's epilogue reads

    // stage Q once (32 x 192 bf16)
#pragma unroll
    for (int i = 0; i < 3; ++i) {
      int c = i * 256 + tid;
      int row = c / 24, off = (c % 24) * 8;
      *(uint4*)&Qs[row][off] =
          *(const uint4*)&Qb[((size_t)h * T_ + t0 + row) * 192 + off];
    }
    if (tid < 32) { m_s[tid] = -INFINITY; l_s[tid] = 0.f; }

    f32x4 Of[4] = {};
    int ig = t0 + srow;

    int njt = tile + 1;
    for (int jt = 0; jt < njt; ++jt) {
      int j0 = jt * 32;
      __syncthreads();
#pragma unroll
      for (int i = 0; i < 3; ++i) {
        int c = i * 256 + tid;
        int row = c / 24, off = (c % 24) * 8;
        *(uint4*)&Ks[row][off] =
            *(const uint4*)&Kb[((size_t)h * T_ + j0 + row) * 192 + off];
      }
#pragma unroll
      for (int i = 0; i < 2; ++i) {
        int c = i * 256 + tid;
        int d = c >> 2, off = (c & 3) * 8;
        *(uint4*)&VsT[d][off] =
            *(const uint4*)&Vt[((size_t)h * 128 + d) * T_ + j0 + off];
      }
      __syncthreads();

      f32x4 Sacc = {};
#pragma unroll
      for (int kk = 0; kk < 6; ++kk) {
        bf16x8 a = *(const bf16x8*)&Qs[16 * wr + l16][kk * 32 + quad * 8];
        bf16x8 b = *(const bf16x8*)&Ks[16 * wc + l16][kk * 32 + quad * 8];
        Sacc = __builtin_amdgcn_mfma_f32_16x16x32_bf16(a, b, Sacc, 0, 0, 0);
      }
#pragma unroll
      for (int r = 0; r < 4; ++r)
        Ss[16 * wr + quad * 4 + r][16 * wc + l16] = Sacc[r];
      __syncthreads();

      float mold = m_s[srow];
      unsigned int kt = kth[ig];
      float4 s4 = *(const float4*)(scores + (size_t)ig * T_ + j0 + 4 * c8);
      float sv[4] = {s4.x, s4.y, s4.z, s4.w};
      float v[4];
#pragma unroll
      for (int c = 0; c < 4; ++c) {
        int jg = j0 + 4 * c8 + c;
        float sc = Ss[srow][4 * c8 + c];
        bool ok = (jg <= ig) && (mono(sv[c]) >= kt);
        v[c] = ok ? sc * SCALE_ : -INFINITY;
      }
      float tmax = fmaxf(fmaxf(v[0], v[1]), fmaxf(v[2], v[3]));
#pragma unroll
      for (int o = 1; o < 8; o <<= 1) tmax = fmaxf(tmax, __shfl_xor(tmax, o, 8));
      float mn = fmaxf(mold, tmax);
      float alpha = (mold == -INFINITY) ? 0.f : expf(mold - mn);
      float p[4], psum = 0.f;
#pragma unroll
      for (int c = 0; c < 4; ++c) {
        p[c] = (v[c] == -INFINITY) ? 0.f : expf(v[c] - mn);
        psum += p[c];
      }
#pragma unroll
      for (int o = 1; o < 8; o <<= 1) psum += __shfl_xor(psum, o, 8);
      if (c8 == 0) {
        m_s[srow] = mn;
        al_s[srow] = alpha;
        l_s[srow] = alpha * l_s[srow] + psum;
      }
#pragma unroll
      for (int c = 0; c < 4; ++c) Ps[srow][4 * c8 + c] = f2bf(p[c]);
      __syncthreads();

      float arow[4];
#pragma unroll
      for (int r = 0; r < 4; ++r) arow[r] = al_s[16 * wr + quad * 4 + r];
      bf16x8 pa = *(const bf16x8*)&Ps[16 * wr + l16][quad * 8];
#pragma unroll
      for (int i = 0; i < 4; ++i) {
#pragma unroll
        for (int r = 0; r < 4; ++r) Of[i][r] *= arow[r];
        bf16x8 vb = *(const bf16x8*)&VsT[16 * (4 * wc + i) + l16][quad * 8];
        Of[i] = __builtin_amdgcn_mfma_f32_16x16x32_bf16(pa, vb, Of[i], 0, 0, 0);
      }
    }

    // epilogue: normalize and write bf16 O (t, h*128+col)
    float linv[4];
#pragma unroll
    for (int r = 0; r < 4; ++r) linv[r] = 1.f / l_s[16 * wr + quad * 4 + r];
#pragma unroll
    for (int i = 0; i < 4; ++i) {
#pragma unroll
      for (int r = 0; r < 4; ++r) {
        int row = t0 + 16 * wr + quad * 4 + r;
        int col = 16 * (4 * wc + i) + l16;
        obf[(size_t)row * 2048 + h * 128 + col] = f2bf(Of[i][r] * linv[r]);
      }
    }
  }
}

}  // namespace

extern "C" void kernel_launch(void* const* d_in, const int* in_sizes, int n_in,
                              void* d_out, int out_size, void* d_ws, size_t ws_size,
                              hipStream_t stream) {
  (void)in_sizes; (void)n_in; (void)out_size; (void)ws_size;
  const int*   positions = (const int*)d_in[0];
  const float* hidden  = (const float*)d_in[1];
  const float* q_c     = (const float*)d_in[2];
  const float* kv_c    = (const float*)d_in[3];
  const float* k_pe    = (const float*)d_in[4];
  const float* q_ln    = (const float*)d_in[5];
  const float* kv_ln   = (const float*)d_in[6];
  const float* Wq_b    = (const float*)d_in[7];
  const float* Wkv_b   = (const float*)d_in[8];
  const float* Wo      = (const float*)d_in[9];
  const float* Wiq     = (const float*)d_in[10];
  const float* Wik     = (const float*)d_in[11];
  const float* ik_g    = (const float*)d_in[12];
  const float* ik_b    = (const float*)d_in[13];
  const float* Ww      = (const float*)d_in[14];
  float* out = (float*)d_out;

  float* ws = (float*)d_ws;
  size_t off = 0;
  float* cosT = ws + off; off += (size_t)T_ * 32;
  float* sinT = ws + off; off += (size_t)T_ * 32;
  float* qcn  = ws + off; off += (size_t)T_ * QLR_;   // slot reused: qcn_lo (bf16)
  float* kvn  = ws + off; off += (size_t)T_ * KVLR_;  // slot reused: kidx hi/lo (bf16)
  float* qbuf = ws + off; off += (size_t)T_ * H_ * 192;  // early overlay: Wiqt hi/lo
  float* kvb  = ws + off; off += (size_t)T_ * H_ * 256;
  float* qidx = ws + off; off += (size_t)T_ * 4096;   // f32; later overlay: Qb/Kb/obf
  float* kidx = ws + off; off += (size_t)T_ * ID_;    // unused (layout stability)
  float* widx = ws + off; off += (size_t)T_ * IH_;
  float* kper = ws + off; off += (size_t)T_ * 64;
  float* scores = ws + off; off += (size_t)T_ * T_;   // early: Wqt+Wkvt, then hgemm partials
  unsigned int* kth = (unsigned int*)(ws + off); off += T_;
  unsigned short* qcn_bf = (unsigned short*)(ws + off); off += (size_t)T_ * QLR_ / 2;
  unsigned short* kvn_bf = (unsigned short*)(ws + off); off += (size_t)T_ * KVLR_ / 2;
  unsigned short* Wot = (unsigned short*)(ws + off); off += (size_t)HID_ * 2048 / 2;
  unsigned short* Vt  = (unsigned short*)(ws + off); off += (size_t)H_ * 128 * T_ / 2;
  unsigned short* qidx_h = (unsigned short*)(ws + off); off += (size_t)T_ * 4096 / 2;
  unsigned short* qidx_l = (unsigned short*)(ws + off); off += (size_t)T_ * 4096 / 2;
  // combined [Wik|Ww]^T bf16 hi/lo (160 x 7168)
  unsigned short* Bikw_h = (unsigned short*)(ws + off); off += (size_t)NC_ * HID_ / 2;
  unsigned short* Bikw_l = (unsigned short*)(ws + off); off += (size_t)NC_ * HID_ / 2;
  (void)kidx;

  // overlays
  unsigned short* Wqt  = (unsigned short*)scores;                  // 3072x1536 bf16
  unsigned short* Wkvt = Wqt + (size_t)3072 * 1536;                // 4096x512 bf16
  float* hpart = scores;                                           // [KSPLIT][T][160] f32
  unsigned short* Qb   = (unsigned short*)qidx;                    // (16,2048,192)
  unsigned short* Kb   = Qb + (size_t)H_ * T_ * 192;               // (16,2048,192)
  unsigned short* obf  = Kb + (size_t)H_ * T_ * 192;               // (2048,2048)
  unsigned short* qcn_lo = (unsigned short*)qcn;                   // T x 1536 bf16
  unsigned short* kidx_h = (unsigned short*)kvn;                   // T x 128 bf16
  unsigned short* kidx_l = kidx_h + (size_t)T_ * ID_;
  unsigned short* Wiqt_h = (unsigned short*)qbuf;                  // 4096x1536 bf16 (dead before Wq GEMM)
  unsigned short* Wiqt_l = Wiqt_h + (size_t)4096 * QLR_;

  k_tables<<<dim3(T_ * 32 / 256), dim3(256), 0, stream>>>(positions, cosT, sinT);
  k_rms<QLR_><<<dim3(T_), dim3(256), 0, stream>>>(q_c, q_ln, qcn_bf, qcn_lo);
  k_rms<KVLR_><<<dim3(T_), dim3(256), 0, stream>>>(kv_c, kv_ln, kvn_bf, nullptr);
  // indexer qidx GEMM first (Wiqt overlays qbuf, which the Wq GEMM overwrites later)
  k_tc2<<<dim3(4096 / 64, QLR_ / 64), dim3(256), 0, stream>>>(Wiq, Wiqt_h, Wiqt_l, QLR_, 4096);
  k_gemm3<<<dim3(4096 / 128, T_ / 128), dim3(256), 0, stream>>>(qcn_bf, qcn_lo, Wiqt_h, Wiqt_l,
                                                                qidx, T_, 4096, QLR_);
  k_qidx_prep<<<dim3(T_), dim3(256), 0, stream>>>(qidx, cosT, sinT, qidx_h, qidx_l);
  // attention-path weight casts + GEMMs (consume Wqt/Wkvt before hgemm partials overwrite)
  k_tc<<<dim3(3072 / 64, QLR_ / 64), dim3(256), 0, stream>>>(Wq_b, Wqt, QLR_, 3072);
  k_tc<<<dim3(4096 / 64, KVLR_ / 64), dim3(256), 0, stream>>>(Wkv_b, Wkvt, KVLR_, 4096);
  k_tc<<<dim3(HID_ / 64, 2048 / 64), dim3(256), 0, stream>>>(Wo, Wot, 2048, HID_);
  k_tc2w<<<dim3(HID_ / 64, 3), dim3(256), 0, stream>>>(Wik, Ww, Bikw_h, Bikw_l);
  k_gemm_bf<<<dim3(3072 / 128, T_ / 128), dim3(256), 0, stream>>>(qcn_bf, Wqt, qbuf, T_, 3072, QLR_);
  k_rope_q<<<dim3(T_ * H_ * 32 / 256), dim3(256), 0, stream>>>(qbuf, cosT, sinT);
  k_gemm_bf<<<dim3(4096 / 128, T_ / 128), dim3(256), 0, stream>>>(kvn_bf, Wkvt, kvb, T_, 4096, KVLR_);
  // fused hidden GEMM (partials into scores region; Wqt/Wkvt now dead)
  k_hgemm<<<dim3(KSPLIT_, T_ / 64), dim3(256), 0, stream>>>(hidden, Bikw_h, Bikw_l, hpart);
  k_kidx_fin<<<dim3(T_), dim3(192), 0, stream>>>(hpart, ik_g, ik_b, cosT, sinT,
                                                 kidx_h, kidx_l, widx);
  k_rope_kpe<<<dim3(T_ * 32 / 256), dim3(256), 0, stream>>>(k_pe, cosT, sinT, kper);
  // scores AFTER fin (scores region overwrites hgemm partials)
  k_scores3<<<dim3(T_ / 64, T_ / 32), dim3(256), 0, stream>>>(qidx_h, qidx_l, kidx_h, kidx_l,
                                                              widx, scores);
  k_topk<<<dim3(T_), dim3(256), 0, stream>>>(scores, kth);
  // casts AFTER k_qidx_prep (Qb/Kb/obf overlay the dead f32 qidx)
  k_cast_flash<<<dim3(T_), dim3(256), 0, stream>>>(qbuf, kvb, kper, Qb, Kb);
  k_cast_v<<<dim3(T_ / 128, H_), dim3(256), 0, stream>>>(kvb, Vt);
  k_flash5<<<dim3(512), dim3(256), 0, stream>>>(Qb, Kb, Vt, scores, kth, obf);
  k_gemm_bf<<<dim3(HID_ / 128, T_ / 128), dim3(256), 0, stream>>>(obf, Wot, out, T_, HID_, 2048);
}